// Round 1
// baseline (646.918 us; speedup 1.0000x reference)
//
#include <hip/hip_runtime.h>
#include <math.h>

#define TPB 256

// ---------------- helpers ----------------
__device__ __forceinline__ void fma4(float4& o, float s, const float4& v){
  o.x += s*v.x; o.y += s*v.y; o.z += s*v.z; o.w += s*v.w;
}
__device__ __forceinline__ void scale4(float4& o, float s){
  o.x *= s; o.y *= s; o.z *= s; o.w *= s;
}
__device__ __forceinline__ float wave_reduce_sum(float v){
  #pragma unroll
  for(int o=32;o>0;o>>=1) v += __shfl_xor(v, o, 64);
  return v;
}

// ---------------- input MLP: X = tanh(yseg @ W1^T + b1) @ W2^T + b2 ----------------
// grid 256 blocks (64 tokens each, same segment), 256 thr
__global__ __launch_bounds__(256) void k_in(
    const float* __restrict__ y,
    const float* __restrict__ w1s0, const float* __restrict__ w1s1,
    const float* __restrict__ w1s2, const float* __restrict__ w1s3,
    const float* __restrict__ b1g, const float* __restrict__ w2g,
    const float* __restrict__ b2g, float* __restrict__ X)
{
  __shared__ float sA[64*68];    // A^T chunk [64k][64m+pad]
  __shared__ float sW1[64*132];  // W1^T chunk [64k][128n+pad]
  __shared__ float sH[128*68];   // H^T [128k][64m+pad]
  __shared__ float sW2[128*68];  // W2^T [128k][64n+pad]
  const int tid = threadIdx.x;
  const int tok0 = blockIdx.x*64;
  const int seg = (tok0 & 1023) >> 8;
  const int F = 64 << seg;
  const float* w1 = seg==0?w1s0: seg==1?w1s1: seg==2?w1s2: w1s3;
  const float* w2 = w2g + seg*64*128;
  const float* b1 = b1g + seg*128;
  const float* b2 = b2g + seg*64;

  for(int i=tid;i<64*128;i+=TPB){ int n=i>>7, kk=i&127; sW2[kk*68+n]=w2[i]; }

  const int tx = tid & 15, ty = tid >> 4;
  const int n0 = tx*8, m0 = ty*4;
  float acc[4][8];
  #pragma unroll
  for(int i=0;i<4;i++){
    #pragma unroll
    for(int j=0;j<8;j++) acc[i][j]=0.f;
  }

  for(int kt=0;kt<F;kt+=64){
    __syncthreads();
    for(int i=tid;i<64*64;i+=TPB){ int m=i>>6, kk=i&63; sA[kk*68+m]=y[(tok0+m)*512 + kt + kk]; }
    for(int i=tid;i<128*64;i+=TPB){ int n=i>>6, kk=i&63; sW1[kk*132+n]=w1[n*F + kt + kk]; }
    __syncthreads();
    for(int kk=0;kk<64;kk++){
      float4 a=*(float4*)&sA[kk*68+m0];
      float av[4]={a.x,a.y,a.z,a.w};
      #pragma unroll
      for(int j4=0;j4<2;j4++){
        float4 w=*(float4*)&sW1[kk*132+n0+j4*4];
        float wv[4]={w.x,w.y,w.z,w.w};
        #pragma unroll
        for(int i=0;i<4;i++){
          #pragma unroll
          for(int j=0;j<4;j++) acc[i][j4*4+j] += av[i]*wv[j];
        }
      }
    }
  }
  // tanh + store H^T
  #pragma unroll
  for(int j=0;j<8;j++){
    float bb = b1[n0+j];
    float4 hv;
    hv.x = tanhf(acc[0][j] + bb);
    hv.y = tanhf(acc[1][j] + bb);
    hv.z = tanhf(acc[2][j] + bb);
    hv.w = tanhf(acc[3][j] + bb);
    *(float4*)&sH[(n0+j)*68 + m0] = hv;
  }
  __syncthreads();
  // GEMM2: 64m x 64n, K=128
  const int n0b = tx*4, m0b = ty*4;
  float a2[4][4];
  #pragma unroll
  for(int i=0;i<4;i++){
    #pragma unroll
    for(int j=0;j<4;j++) a2[i][j]=0.f;
  }
  for(int kk=0;kk<128;kk++){
    float4 a=*(float4*)&sH[kk*68+m0b];
    float4 w=*(float4*)&sW2[kk*68+n0b];
    float av[4]={a.x,a.y,a.z,a.w}, wv[4]={w.x,w.y,w.z,w.w};
    #pragma unroll
    for(int i=0;i<4;i++){
      #pragma unroll
      for(int j=0;j<4;j++) a2[i][j]+=av[i]*wv[j];
    }
  }
  #pragma unroll
  for(int i=0;i<4;i++){
    float4 o;
    o.x=a2[i][0]+b2[n0b+0];
    o.y=a2[i][1]+b2[n0b+1];
    o.z=a2[i][2]+b2[n0b+2];
    o.w=a2[i][3]+b2[n0b+3];
    *(float4*)&X[(tok0+m0b+i)*64+n0b]=o;
  }
}

// ---------------- generic token GEMM: out = act(A @ W^T + b) [+res, LN] ----------------
template<int K, int N, int SA, int SO, int ACT, bool LNORM>
__global__ __launch_bounds__(256) void k_gemm(
    const float* __restrict__ A, const float* __restrict__ W,
    const float* __restrict__ bias, float* __restrict__ out,
    const float* __restrict__ res, const float* __restrict__ lnw,
    const float* __restrict__ lnb)
{
  constexpr int NN = N/16;
  constexpr int WS = N+4;
  __shared__ float sW[K*WS];
  __shared__ float sA[64*68];
  __shared__ float sMean[64];
  __shared__ float sRstd[64];
  const int tid=threadIdx.x;
  const int tok0=blockIdx.x*64;
  for(int i=tid;i<N*K;i+=TPB){ int n=i/K, kk=i%K; sW[kk*WS+n]=W[i]; }
  const int tx=tid&15, ty=tid>>4;
  const int n0=tx*NN, m0=ty*4;
  float acc[4][NN];
  #pragma unroll
  for(int i=0;i<4;i++){
    #pragma unroll
    for(int j=0;j<NN;j++) acc[i][j]=0.f;
  }
  for(int kt=0;kt<K;kt+=64){
    __syncthreads();
    for(int i=tid;i<64*64;i+=TPB){ int m=i>>6, kk=i&63; sA[kk*68+m]=A[(tok0+m)*SA + kt + kk]; }
    __syncthreads();
    for(int kk=0;kk<64;kk++){
      float4 a=*(float4*)&sA[kk*68+m0];
      float av[4]={a.x,a.y,a.z,a.w};
      #pragma unroll
      for(int j4=0;j4<NN/4;j4++){
        float4 w=*(float4*)&sW[(kt+kk)*WS+n0+j4*4];
        float wv[4]={w.x,w.y,w.z,w.w};
        #pragma unroll
        for(int i=0;i<4;i++){
          #pragma unroll
          for(int j=0;j<4;j++) acc[i][j4*4+j]+=av[i]*wv[j];
        }
      }
    }
  }
  if constexpr(!LNORM){
    #pragma unroll
    for(int i=0;i<4;i++){
      const int row=tok0+m0+i;
      #pragma unroll
      for(int j4=0;j4<NN/4;j4++){
        float4 o;
        o.x=acc[i][j4*4+0]+bias[n0+j4*4+0];
        o.y=acc[i][j4*4+1]+bias[n0+j4*4+1];
        o.z=acc[i][j4*4+2]+bias[n0+j4*4+2];
        o.w=acc[i][j4*4+3]+bias[n0+j4*4+3];
        if(ACT==1){ o.x=fmaxf(o.x,0.f); o.y=fmaxf(o.y,0.f); o.z=fmaxf(o.z,0.f); o.w=fmaxf(o.w,0.f); }
        *(float4*)&out[row*SO+n0+j4*4]=o;
      }
    }
  } else {
    __syncthreads();
    #pragma unroll
    for(int i=0;i<4;i++){
      const int row=tok0+m0+i;
      float4 r4=*(const float4*)&res[row*64+n0];
      float4 v;
      v.x=acc[i][0]+bias[n0+0]+r4.x;
      v.y=acc[i][1]+bias[n0+1]+r4.y;
      v.z=acc[i][2]+bias[n0+2]+r4.z;
      v.w=acc[i][3]+bias[n0+3]+r4.w;
      *(float4*)&sA[(m0+i)*68+n0]=v;
    }
    __syncthreads();
    if(tid<64){
      float s=0.f,s2=0.f;
      for(int n=0;n<64;n++){ float x=sA[tid*68+n]; s+=x; s2+=x*x; }
      float mean=s*0.015625f;
      float var=s2*0.015625f-mean*mean;
      sMean[tid]=mean; sRstd[tid]=rsqrtf(var+1e-5f);
    }
    __syncthreads();
    for(int i=tid;i<64*64;i+=TPB){
      int m=i>>6, n=i&63;
      out[(tok0+m)*64+n]=(sA[m*68+n]-sMean[m])*sRstd[m]*lnw[n]+lnb[n];
    }
  }
}

// ---------------- attention: flash-style, QT=256 per block ----------------
// grid 256 = 16 b * 4 h * 4 qtiles. qkv stride 192: q@0, k@64, v@128, head h at h*16
__global__ __launch_bounds__(256) void k_attn(const float* __restrict__ qkv, float* __restrict__ O)
{
  __shared__ float sQ[16*260];   // Q^T [d][256q+pad]
  __shared__ float sK[16*68];    // K^T [d][64k+pad]
  __shared__ float sV[64*20];    // V [64k][16d+pad]
  __shared__ float sS[64*260];   // S^T [64k][256q+pad]
  __shared__ float sAlpha[256];
  __shared__ float sLinv[256];
  const int tid=threadIdx.x;
  const int qt = blockIdx.x & 3;
  const int h  = (blockIdx.x>>2) & 3;
  const int b  = blockIdx.x>>4;
  const int t0 = b*1024 + qt*256;

  // load Q tile transposed
  {
    const int r = tid>>2, d4 = (tid&3)*4;
    #pragma unroll
    for(int c=0;c<4;c++){
      int q = r + 64*c;
      float4 v = *(const float4*)&qkv[(t0+q)*192 + h*16 + d4];
      sQ[(d4+0)*260+q]=v.x; sQ[(d4+1)*260+q]=v.y; sQ[(d4+2)*260+q]=v.z; sQ[(d4+3)*260+q]=v.w;
    }
  }
  float mreg=-INFINITY, lreg=0.f;                 // softmax state: this thread owns q = tid
  float4 o0={0,0,0,0}, o1=o0, o2=o0, o3=o0;        // PV accum: q0..q0+3 x d0..d0+3
  const int pv_q0 = (tid>>2)*4, pv_d0 = (tid&3)*4;
  const int sc_q0 = (tid>>2)*4, sc_k0 = (tid&3)*16;
  __syncthreads();

  for(int kt=0;kt<16;kt++){
    const int k0g = kt*64;
    // load K^T, V tiles
    {
      const int r = tid>>2, d4=(tid&3)*4;
      const float* base = &qkv[(b*1024 + k0g + r)*192 + h*16];
      float4 kv = *(const float4*)&base[64 + d4];
      sK[(d4+0)*68+r]=kv.x; sK[(d4+1)*68+r]=kv.y; sK[(d4+2)*68+r]=kv.z; sK[(d4+3)*68+r]=kv.w;
      float4 vv = *(const float4*)&base[128 + d4];
      *(float4*)&sV[r*20+d4]=vv;
    }
    __syncthreads();
    // S = Q K^T * 0.25  (4q x 16k per thread)
    {
      float acc[4][16];
      #pragma unroll
      for(int i=0;i<4;i++){
        #pragma unroll
        for(int j=0;j<16;j++) acc[i][j]=0.f;
      }
      for(int d=0;d<16;d++){
        float4 qv=*(float4*)&sQ[d*260+sc_q0];
        float qa[4]={qv.x,qv.y,qv.z,qv.w};
        #pragma unroll
        for(int j4=0;j4<4;j4++){
          float4 kv=*(float4*)&sK[d*68+sc_k0+j4*4];
          float ka[4]={kv.x,kv.y,kv.z,kv.w};
          #pragma unroll
          for(int i=0;i<4;i++){
            #pragma unroll
            for(int j=0;j<4;j++) acc[i][j4*4+j]+=qa[i]*ka[j];
          }
        }
      }
      #pragma unroll
      for(int j=0;j<16;j++){
        float4 s4={acc[0][j]*0.25f, acc[1][j]*0.25f, acc[2][j]*0.25f, acc[3][j]*0.25f};
        *(float4*)&sS[(sc_k0+j)*260 + sc_q0]=s4;
      }
    }
    __syncthreads();
    // online softmax, one thread per q row (q = tid)
    {
      float r[64];
      #pragma unroll
      for(int k=0;k<64;k++) r[k]=sS[k*260+tid];
      float mx=mreg;
      #pragma unroll
      for(int k=0;k<64;k++) mx=fmaxf(mx,r[k]);
      float alpha=__expf(mreg-mx);
      float sum=0.f;
      #pragma unroll
      for(int k=0;k<64;k++){ float p=__expf(r[k]-mx); sum+=p; sS[k*260+tid]=p; }
      lreg=lreg*alpha+sum; mreg=mx;
      sAlpha[tid]=alpha;
    }
    __syncthreads();
    // O = O*alpha + P V
    {
      float4 a4=*(float4*)&sAlpha[pv_q0];
      scale4(o0,a4.x); scale4(o1,a4.y); scale4(o2,a4.z); scale4(o3,a4.w);
      for(int k=0;k<64;k++){
        float4 p4=*(float4*)&sS[k*260+pv_q0];
        float4 v4=*(float4*)&sV[k*20+pv_d0];
        fma4(o0,p4.x,v4); fma4(o1,p4.y,v4); fma4(o2,p4.z,v4); fma4(o3,p4.w,v4);
      }
    }
    __syncthreads();
  }
  sLinv[tid]=1.f/lreg;
  __syncthreads();
  float4 li=*(float4*)&sLinv[pv_q0];
  scale4(o0,li.x); scale4(o1,li.y); scale4(o2,li.z); scale4(o3,li.w);
  *(float4*)&O[(t0+pv_q0+0)*64 + h*16 + pv_d0]=o0;
  *(float4*)&O[(t0+pv_q0+1)*64 + h*16 + pv_d0]=o1;
  *(float4*)&O[(t0+pv_q0+2)*64 + h*16 + pv_d0]=o2;
  *(float4*)&O[(t0+pv_q0+3)*64 + h*16 + pv_d0]=o3;
}

// ---------------- output head + ke ----------------
__global__ __launch_bounds__(256) void k_out(
    const float* __restrict__ X,
    const float* __restrict__ ow1g, const float* __restrict__ ob1g,
    const float* __restrict__ w2s0, const float* __restrict__ w2s1,
    const float* __restrict__ w2s2, const float* __restrict__ w2s3,
    const float* __restrict__ b2s0, const float* __restrict__ b2s1,
    const float* __restrict__ b2s2, const float* __restrict__ b2s3,
    float* __restrict__ out0, float* __restrict__ ke)
{
  __shared__ float sA[64*68];
  __shared__ float sW1[64*132];
  __shared__ float sH[128*68];
  __shared__ float sW2[128*68];
  const int tid=threadIdx.x;
  const int tok0=blockIdx.x*64;
  const int seg=(tok0&1023)>>8;
  const int F=64<<seg;
  const int b=tok0>>10;
  const float* w1=ow1g + seg*128*64;
  const float* b1=ob1g + seg*128;
  const float* w2 = seg==0?w2s0: seg==1?w2s1: seg==2?w2s2: w2s3;
  const float* b2 = seg==0?b2s0: seg==1?b2s1: seg==2?b2s2: b2s3;

  for(int i=tid;i<64*64;i+=TPB){ int m=i>>6, kk=i&63; sA[kk*68+m]=X[(tok0+m)*64+kk]; }
  for(int i=tid;i<128*64;i+=TPB){ int n=i>>6, kk=i&63; sW1[kk*132+n]=w1[i]; }
  __syncthreads();
  const int tx=tid&15, ty=tid>>4;
  const int n0=tx*8, m0=ty*4;
  float acc[4][8];
  #pragma unroll
  for(int i=0;i<4;i++){
    #pragma unroll
    for(int j=0;j<8;j++) acc[i][j]=0.f;
  }
  for(int kk=0;kk<64;kk++){
    float4 a=*(float4*)&sA[kk*68+m0];
    float av[4]={a.x,a.y,a.z,a.w};
    #pragma unroll
    for(int j4=0;j4<2;j4++){
      float4 w=*(float4*)&sW1[kk*132+n0+j4*4];
      float wv[4]={w.x,w.y,w.z,w.w};
      #pragma unroll
      for(int i=0;i<4;i++){
        #pragma unroll
        for(int j=0;j<4;j++) acc[i][j4*4+j]+=av[i]*wv[j];
      }
    }
  }
  #pragma unroll
  for(int j=0;j<8;j++){
    float bb=b1[n0+j];
    float4 hv;
    hv.x=tanhf(acc[0][j]+bb);
    hv.y=tanhf(acc[1][j]+bb);
    hv.z=tanhf(acc[2][j]+bb);
    hv.w=tanhf(acc[3][j]+bb);
    *(float4*)&sH[(n0+j)*68+m0]=hv;
  }
  float keacc=0.f;
  const int n0b=tx*4, m0b=ty*4;
  for(int nc=0;nc<8;nc++){
    const int nbase=nc*64;
    if(nbase<F){
      __syncthreads();
      for(int i=tid;i<128*64;i+=TPB){ int n=i>>7, kk=i&127; sW2[kk*68+n]=w2[(nbase+n)*128+kk]; }
      __syncthreads();
      float a2[4][4];
      #pragma unroll
      for(int i=0;i<4;i++){
        #pragma unroll
        for(int j=0;j<4;j++) a2[i][j]=0.f;
      }
      for(int kk=0;kk<128;kk++){
        float4 a=*(float4*)&sH[kk*68+m0b];
        float4 w=*(float4*)&sW2[kk*68+n0b];
        float av[4]={a.x,a.y,a.z,a.w}, wv[4]={w.x,w.y,w.z,w.w};
        #pragma unroll
        for(int i=0;i<4;i++){
          #pragma unroll
          for(int j=0;j<4;j++) a2[i][j]+=av[i]*wv[j];
        }
      }
      #pragma unroll
      for(int i=0;i<4;i++){
        float4 d;
        d.x=a2[i][0]+b2[nbase+n0b+0];
        d.y=a2[i][1]+b2[nbase+n0b+1];
        d.z=a2[i][2]+b2[nbase+n0b+2];
        d.w=a2[i][3]+b2[nbase+n0b+3];
        keacc += d.x*d.x+d.y*d.y+d.z*d.z+d.w*d.w;
        *(float4*)&out0[(tok0+m0b+i)*512 + nbase+n0b]=d;
      }
    } else {
      for(int i=tid;i<1024;i+=TPB){
        int m=i>>4, n4=(i&15)*4;
        float4 z={0.f,0.f,0.f,0.f};
        *(float4*)&out0[(tok0+m)*512 + nbase + n4]=z;
      }
    }
  }
  float tot=wave_reduce_sum(keacc);
  if((tid&63)==0) atomicAdd(&ke[b], 0.5f*tot);
}

// ---------------- launch ----------------
extern "C" void kernel_launch(void* const* d_in, const int* in_sizes, int n_in,
                              void* d_out, int out_size, void* d_ws, size_t ws_size,
                              hipStream_t stream)
{
  const float* y      = (const float*)d_in[1];
  const float* w1s[4] = {(const float*)d_in[3],(const float*)d_in[4],(const float*)d_in[5],(const float*)d_in[6]};
  const float* w2s[4] = {(const float*)d_in[7],(const float*)d_in[8],(const float*)d_in[9],(const float*)d_in[10]};
  const float* b2s[4] = {(const float*)d_in[11],(const float*)d_in[12],(const float*)d_in[13],(const float*)d_in[14]};
  const float* in_b1  = (const float*)d_in[15];
  const float* in_w2  = (const float*)d_in[16];
  const float* in_b2  = (const float*)d_in[17];
  const float* out_w1 = (const float*)d_in[18];
  const float* out_b1 = (const float*)d_in[19];
  const float* qkv_w  = (const float*)d_in[20];
  const float* qkv_b  = (const float*)d_in[21];
  const float* ao_w   = (const float*)d_in[22];
  const float* ao_b   = (const float*)d_in[23];
  const float* ln1w   = (const float*)d_in[24];
  const float* ln1b   = (const float*)d_in[25];
  const float* fw1    = (const float*)d_in[26];
  const float* fb1    = (const float*)d_in[27];
  const float* fw2    = (const float*)d_in[28];
  const float* fb2    = (const float*)d_in[29];
  const float* ln2w   = (const float*)d_in[30];
  const float* ln2b   = (const float*)d_in[31];

  float* out0 = (float*)d_out;
  float* keo  = out0 + (size_t)16*1024*512;

  float* X  = (float*)d_ws;                 // 16384 x 64
  float* T1 = X  + (size_t)16384*64;        // 16384 x 256 (qkv uses stride 192)
  float* O  = T1 + (size_t)16384*256;       // 16384 x 64

  k_in<<<256,TPB,0,stream>>>(y, w1s[0],w1s[1],w1s[2],w1s[3], in_b1, in_w2, in_b2, X);

  for(int l=0;l<2;l++){
    k_gemm<64,192,64,192,0,false><<<256,TPB,0,stream>>>(X, qkv_w + l*192*64, qkv_b + l*192, T1, nullptr,nullptr,nullptr);
    k_attn<<<256,TPB,0,stream>>>(T1, O);
    k_gemm<64,64,64,64,0,true><<<256,TPB,0,stream>>>(O, ao_w + l*64*64, ao_b + l*64, X, X, ln1w + l*64, ln1b + l*64);
    k_gemm<64,256,64,256,1,false><<<256,TPB,0,stream>>>(X, fw1 + l*256*64, fb1 + l*256, T1, nullptr,nullptr,nullptr);
    k_gemm<256,64,256,64,0,true><<<256,TPB,0,stream>>>(T1, fw2 + l*64*256, fb2 + l*64, X, X, ln2w + l*64, ln2b + l*64);
  }

  hipMemsetAsync(keo, 0, 16*sizeof(float), stream);
  k_out<<<256,TPB,0,stream>>>(X, out_w1, out_b1,
      w2s[0],w2s[1],w2s[2],w2s[3], b2s[0],b2s[1],b2s[2],b2s[3], out0, keo);
}

// Round 2
// 512.329 us; speedup vs baseline: 1.2627x; 1.2627x over previous
//
#include <hip/hip_runtime.h>
#include <math.h>

#define TPB 256

typedef short bf8v __attribute__((ext_vector_type(8)));
typedef float f4v  __attribute__((ext_vector_type(4)));

__device__ __forceinline__ float wave_reduce_sum(float v){
  #pragma unroll
  for(int o=32;o>0;o>>=1) v += __shfl_xor(v, o, 64);
  return v;
}
__device__ __forceinline__ ushort bf16_rne(float f){
  uint u = __float_as_uint(f);
  u += 0x7fffu + ((u>>16)&1u);
  return (ushort)(u>>16);
}

// ---------------- input MLP: X = tanh(yseg @ W1^T + b1) @ W2^T + b2 ----------------
__global__ __launch_bounds__(256) void k_in(
    const float* __restrict__ y,
    const float* __restrict__ w1s0, const float* __restrict__ w1s1,
    const float* __restrict__ w1s2, const float* __restrict__ w1s3,
    const float* __restrict__ b1g, const float* __restrict__ w2g,
    const float* __restrict__ b2g, float* __restrict__ X)
{
  __shared__ float sA[64*68];
  __shared__ float sW1[64*132];
  __shared__ float sH[128*68];
  __shared__ float sW2[128*68];
  const int tid = threadIdx.x;
  const int tok0 = blockIdx.x*64;
  const int seg = (tok0 & 1023) >> 8;
  const int F = 64 << seg;
  const float* w1 = seg==0?w1s0: seg==1?w1s1: seg==2?w1s2: w1s3;
  const float* w2 = w2g + seg*64*128;
  const float* b1 = b1g + seg*128;
  const float* b2 = b2g + seg*64;

  for(int i=tid;i<64*128;i+=TPB){ int n=i>>7, kk=i&127; sW2[kk*68+n]=w2[i]; }

  const int tx = tid & 15, ty = tid >> 4;
  const int n0 = tx*8, m0 = ty*4;
  float acc[4][8];
  #pragma unroll
  for(int i=0;i<4;i++){
    #pragma unroll
    for(int j=0;j<8;j++) acc[i][j]=0.f;
  }

  for(int kt=0;kt<F;kt+=64){
    __syncthreads();
    for(int i=tid;i<64*64;i+=TPB){ int m=i>>6, kk=i&63; sA[kk*68+m]=y[(tok0+m)*512 + kt + kk]; }
    for(int i=tid;i<128*64;i+=TPB){ int n=i>>6, kk=i&63; sW1[kk*132+n]=w1[n*F + kt + kk]; }
    __syncthreads();
    for(int kk=0;kk<64;kk++){
      float4 a=*(float4*)&sA[kk*68+m0];
      float av[4]={a.x,a.y,a.z,a.w};
      #pragma unroll
      for(int j4=0;j4<2;j4++){
        float4 w=*(float4*)&sW1[kk*132+n0+j4*4];
        float wv[4]={w.x,w.y,w.z,w.w};
        #pragma unroll
        for(int i=0;i<4;i++){
          #pragma unroll
          for(int j=0;j<4;j++) acc[i][j4*4+j] += av[i]*wv[j];
        }
      }
    }
  }
  #pragma unroll
  for(int j=0;j<8;j++){
    float bb = b1[n0+j];
    float4 hv;
    hv.x = tanhf(acc[0][j] + bb);
    hv.y = tanhf(acc[1][j] + bb);
    hv.z = tanhf(acc[2][j] + bb);
    hv.w = tanhf(acc[3][j] + bb);
    *(float4*)&sH[(n0+j)*68 + m0] = hv;
  }
  __syncthreads();
  const int n0b = tx*4, m0b = ty*4;
  float a2[4][4];
  #pragma unroll
  for(int i=0;i<4;i++){
    #pragma unroll
    for(int j=0;j<4;j++) a2[i][j]=0.f;
  }
  for(int kk=0;kk<128;kk++){
    float4 a=*(float4*)&sH[kk*68+m0b];
    float4 w=*(float4*)&sW2[kk*68+n0b];
    float av[4]={a.x,a.y,a.z,a.w}, wv[4]={w.x,w.y,w.z,w.w};
    #pragma unroll
    for(int i=0;i<4;i++){
      #pragma unroll
      for(int j=0;j<4;j++) a2[i][j]+=av[i]*wv[j];
    }
  }
  #pragma unroll
  for(int i=0;i<4;i++){
    float4 o;
    o.x=a2[i][0]+b2[n0b+0];
    o.y=a2[i][1]+b2[n0b+1];
    o.z=a2[i][2]+b2[n0b+2];
    o.w=a2[i][3]+b2[n0b+3];
    *(float4*)&X[(tok0+m0b+i)*64+n0b]=o;
  }
}

// ---------------- generic token GEMM ----------------
template<int K, int N, int SA, int SO, int ACT, bool LNORM>
__global__ __launch_bounds__(256) void k_gemm(
    const float* __restrict__ A, const float* __restrict__ W,
    const float* __restrict__ bias, float* __restrict__ out,
    const float* __restrict__ res, const float* __restrict__ lnw,
    const float* __restrict__ lnb)
{
  constexpr int NN = N/16;
  constexpr int WS = N+4;
  __shared__ float sW[K*WS];
  __shared__ float sA[64*68];
  __shared__ float sMean[64];
  __shared__ float sRstd[64];
  const int tid=threadIdx.x;
  const int tok0=blockIdx.x*64;
  for(int i=tid;i<N*K;i+=TPB){ int n=i/K, kk=i%K; sW[kk*WS+n]=W[i]; }
  const int tx=tid&15, ty=tid>>4;
  const int n0=tx*NN, m0=ty*4;
  float acc[4][NN];
  #pragma unroll
  for(int i=0;i<4;i++){
    #pragma unroll
    for(int j=0;j<NN;j++) acc[i][j]=0.f;
  }
  for(int kt=0;kt<K;kt+=64){
    __syncthreads();
    for(int i=tid;i<64*64;i+=TPB){ int m=i>>6, kk=i&63; sA[kk*68+m]=A[(tok0+m)*SA + kt + kk]; }
    __syncthreads();
    for(int kk=0;kk<64;kk++){
      float4 a=*(float4*)&sA[kk*68+m0];
      float av[4]={a.x,a.y,a.z,a.w};
      #pragma unroll
      for(int j4=0;j4<NN/4;j4++){
        float4 w=*(float4*)&sW[(kt+kk)*WS+n0+j4*4];
        float wv[4]={w.x,w.y,w.z,w.w};
        #pragma unroll
        for(int i=0;i<4;i++){
          #pragma unroll
          for(int j=0;j<4;j++) acc[i][j4*4+j]+=av[i]*wv[j];
        }
      }
    }
  }
  if constexpr(!LNORM){
    #pragma unroll
    for(int i=0;i<4;i++){
      const int row=tok0+m0+i;
      #pragma unroll
      for(int j4=0;j4<NN/4;j4++){
        float4 o;
        o.x=acc[i][j4*4+0]+bias[n0+j4*4+0];
        o.y=acc[i][j4*4+1]+bias[n0+j4*4+1];
        o.z=acc[i][j4*4+2]+bias[n0+j4*4+2];
        o.w=acc[i][j4*4+3]+bias[n0+j4*4+3];
        if(ACT==1){ o.x=fmaxf(o.x,0.f); o.y=fmaxf(o.y,0.f); o.z=fmaxf(o.z,0.f); o.w=fmaxf(o.w,0.f); }
        *(float4*)&out[row*SO+n0+j4*4]=o;
      }
    }
  } else {
    __syncthreads();
    #pragma unroll
    for(int i=0;i<4;i++){
      const int row=tok0+m0+i;
      float4 r4=*(const float4*)&res[row*64+n0];
      float4 v;
      v.x=acc[i][0]+bias[n0+0]+r4.x;
      v.y=acc[i][1]+bias[n0+1]+r4.y;
      v.z=acc[i][2]+bias[n0+2]+r4.z;
      v.w=acc[i][3]+bias[n0+3]+r4.w;
      *(float4*)&sA[(m0+i)*68+n0]=v;
    }
    __syncthreads();
    if(tid<64){
      float s=0.f,s2=0.f;
      for(int n=0;n<64;n++){ float x=sA[tid*68+n]; s+=x; s2+=x*x; }
      float mean=s*0.015625f;
      float var=s2*0.015625f-mean*mean;
      sMean[tid]=mean; sRstd[tid]=rsqrtf(var+1e-5f);
    }
    __syncthreads();
    for(int i=tid;i<64*64;i+=TPB){
      int m=i>>6, n=i&63;
      out[(tok0+m)*64+n]=(sA[m*68+n]-sMean[m])*sRstd[m]*lnw[n]+lnb[n];
    }
  }
}

// ---------------- attention: MFMA bf16, S^T = K Q^T, unnormalized exp2 softmax ----------------
// grid 256 = 16b * 4h * 4 qtiles; 4 waves, each wave owns 64 q rows.
// qkv stride 192: q@0, k@64, v@128, head h at h*16. d=16 padded to K=32.
__global__ __launch_bounds__(256) void k_attn(const float* __restrict__ qkv, float* __restrict__ O)
{
  __shared__ ushort sK[64*40];     // [k][d32 + 8 pad], upper d zeroed
  __shared__ ushort sV[16*72];     // V^T [d][64k + 8 pad]
  __shared__ ushort sP[4][64*72];  // per-wave P [q][64k + 8 pad]
  const int tid  = threadIdx.x;
  const int lane = tid & 63, w = tid >> 6;
  const int ln   = lane & 15, quad = lane >> 4;
  const int qt = blockIdx.x & 3, h = (blockIdx.x >> 2) & 3, b = blockIdx.x >> 4;
  const int rowQ0 = b*1024 + qt*256 + w*64;
  const int rowK0 = b*1024;

  // zero upper-d half of sK (once; staging only writes d<16)
  for(int i=tid;i<1024;i+=TPB){ sK[(i>>4)*40 + 16 + (i&15)] = 0; }

  // Q fragments (B-operand: n=lane&15 -> q, k=quad*8+j -> d), pre-scaled by log2e/4
  const float qs = 0.36067376022224085f;
  union U8 { bf8v v; ushort s[8]; };
  bf8v qf[4];
  #pragma unroll
  for(int s=0;s<4;s++){
    U8 u;
    if(quad<2){
      const float* p = &qkv[(size_t)(rowQ0 + s*16 + ln)*192 + h*16 + quad*8];
      float4 a = *(const float4*)p;
      float4 c = *(const float4*)(p+4);
      u.s[0]=bf16_rne(a.x*qs); u.s[1]=bf16_rne(a.y*qs); u.s[2]=bf16_rne(a.z*qs); u.s[3]=bf16_rne(a.w*qs);
      u.s[4]=bf16_rne(c.x*qs); u.s[5]=bf16_rne(c.y*qs); u.s[6]=bf16_rne(c.z*qs); u.s[7]=bf16_rne(c.w*qs);
    } else {
      #pragma unroll
      for(int j=0;j<8;j++) u.s[j]=0;
    }
    qf[s]=u.v;
  }

  f4v oacc[4];
  #pragma unroll
  for(int s=0;s<4;s++) oacc[s] = (f4v){0.f,0.f,0.f,0.f};
  float lpart[4] = {0.f,0.f,0.f,0.f};

  for(int kc=0;kc<16;kc++){
    __syncthreads();
    // stage K (bf16, [k][d]) and V^T (bf16, [d][k]) for this 64-key chunk
    {
      const int k = tid>>2, part = tid&3;
      const float* src = &qkv[(size_t)(rowK0 + kc*64 + k)*192 + h*16 + part*4];
      float4 kv = *(const float4*)(src + 64);
      float4 vv = *(const float4*)(src + 128);
      uint2 kp;
      kp.x = (uint)bf16_rne(kv.x) | ((uint)bf16_rne(kv.y)<<16);
      kp.y = (uint)bf16_rne(kv.z) | ((uint)bf16_rne(kv.w)<<16);
      *(uint2*)&sK[k*40 + part*4] = kp;
      sV[(part*4+0)*72 + k] = bf16_rne(vv.x);
      sV[(part*4+1)*72 + k] = bf16_rne(vv.y);
      sV[(part*4+2)*72 + k] = bf16_rne(vv.z);
      sV[(part*4+3)*72 + k] = bf16_rne(vv.w);
    }
    __syncthreads();

    ushort* Pw = sP[w];
    // S^T = K * Q^T  (A = K-frag: m=k-idx; B = Q^T-frag: n=q). C/D: row=k-idx, col=q.
    #pragma unroll
    for(int ks=0;ks<4;ks++){
      bf8v kf = *(bf8v*)&sK[(ks*16+ln)*40 + quad*8];
      #pragma unroll
      for(int qs2=0;qs2<4;qs2++){
        f4v st = __builtin_amdgcn_mfma_f32_16x16x32_bf16(kf, qf[qs2], (f4v){0.f,0.f,0.f,0.f}, 0,0,0);
        float p0 = exp2f(st[0]);
        float p1 = exp2f(st[1]);
        float p2 = exp2f(st[2]);
        float p3 = exp2f(st[3]);
        lpart[qs2] += (p0+p1)+(p2+p3);
        uint2 pk;
        pk.x = (uint)bf16_rne(p0) | ((uint)bf16_rne(p1)<<16);
        pk.y = (uint)bf16_rne(p2) | ((uint)bf16_rne(p3)<<16);
        // lane holds rows k = ks*16 + quad*4 + r, col q = qs2*16+ln  ->  P[q][k] 4 consecutive k
        *(uint2*)&Pw[(qs2*16+ln)*72 + ks*16 + quad*4] = pk;
      }
    }
    // O += P * V  (A = P-frag: m=q, k=key; B = V^T-frag: n=d, k=key), K=32 halves
    bf8v vf0 = *(bf8v*)&sV[ln*72 +  0 + quad*8];
    bf8v vf1 = *(bf8v*)&sV[ln*72 + 32 + quad*8];
    #pragma unroll
    for(int qs2=0;qs2<4;qs2++){
      bf8v pa0 = *(bf8v*)&Pw[(qs2*16+ln)*72 +  0 + quad*8];
      bf8v pa1 = *(bf8v*)&Pw[(qs2*16+ln)*72 + 32 + quad*8];
      oacc[qs2] = __builtin_amdgcn_mfma_f32_16x16x32_bf16(pa0, vf0, oacc[qs2], 0,0,0);
      oacc[qs2] = __builtin_amdgcn_mfma_f32_16x16x32_bf16(pa1, vf1, oacc[qs2], 0,0,0);
    }
  }

  // epilogue: l = full softmax denom per q (lane cols), normalize, store
  #pragma unroll
  for(int qs2=0;qs2<4;qs2++){
    float l = lpart[qs2];
    l += __shfl_xor(l, 16, 64);
    l += __shfl_xor(l, 32, 64);
    #pragma unroll
    for(int r=0;r<4;r++){
      float lr = __shfl(l, quad*4 + r, 64);   // lane (quad*4+r) holds l for q = qs2*16+quad*4+r
      float inv = __builtin_amdgcn_rcpf(lr);
      O[(size_t)(rowQ0 + qs2*16 + quad*4 + r)*64 + h*16 + ln] = oacc[qs2][r]*inv;
    }
  }
}

// ---------------- output head + ke ----------------
__global__ __launch_bounds__(256) void k_out(
    const float* __restrict__ X,
    const float* __restrict__ ow1g, const float* __restrict__ ob1g,
    const float* __restrict__ w2s0, const float* __restrict__ w2s1,
    const float* __restrict__ w2s2, const float* __restrict__ w2s3,
    const float* __restrict__ b2s0, const float* __restrict__ b2s1,
    const float* __restrict__ b2s2, const float* __restrict__ b2s3,
    float* __restrict__ out0, float* __restrict__ ke)
{
  __shared__ float sA[64*68];
  __shared__ float sW1[64*132];
  __shared__ float sH[128*68];
  __shared__ float sW2[128*68];
  const int tid=threadIdx.x;
  const int tok0=blockIdx.x*64;
  const int seg=(tok0&1023)>>8;
  const int F=64<<seg;
  const int b=tok0>>10;
  const float* w1=ow1g + seg*128*64;
  const float* b1=ob1g + seg*128;
  const float* w2 = seg==0?w2s0: seg==1?w2s1: seg==2?w2s2: w2s3;
  const float* b2 = seg==0?b2s0: seg==1?b2s1: seg==2?b2s2: b2s3;

  for(int i=tid;i<64*64;i+=TPB){ int m=i>>6, kk=i&63; sA[kk*68+m]=X[(tok0+m)*64+kk]; }
  for(int i=tid;i<128*64;i+=TPB){ int n=i>>6, kk=i&63; sW1[kk*132+n]=w1[i]; }
  __syncthreads();
  const int tx=tid&15, ty=tid>>4;
  const int n0=tx*8, m0=ty*4;
  float acc[4][8];
  #pragma unroll
  for(int i=0;i<4;i++){
    #pragma unroll
    for(int j=0;j<8;j++) acc[i][j]=0.f;
  }
  for(int kk=0;kk<64;kk++){
    float4 a=*(float4*)&sA[kk*68+m0];
    float av[4]={a.x,a.y,a.z,a.w};
    #pragma unroll
    for(int j4=0;j4<2;j4++){
      float4 w=*(float4*)&sW1[kk*132+n0+j4*4];
      float wv[4]={w.x,w.y,w.z,w.w};
      #pragma unroll
      for(int i=0;i<4;i++){
        #pragma unroll
        for(int j=0;j<4;j++) acc[i][j4*4+j]+=av[i]*wv[j];
      }
    }
  }
  #pragma unroll
  for(int j=0;j<8;j++){
    float bb=b1[n0+j];
    float4 hv;
    hv.x=tanhf(acc[0][j]+bb);
    hv.y=tanhf(acc[1][j]+bb);
    hv.z=tanhf(acc[2][j]+bb);
    hv.w=tanhf(acc[3][j]+bb);
    *(float4*)&sH[(n0+j)*68+m0]=hv;
  }
  float keacc=0.f;
  const int n0b=tx*4, m0b=ty*4;
  for(int nc=0;nc<8;nc++){
    const int nbase=nc*64;
    if(nbase<F){
      __syncthreads();
      for(int i=tid;i<128*64;i+=TPB){ int n=i>>7, kk=i&127; sW2[kk*68+n]=w2[(nbase+n)*128+kk]; }
      __syncthreads();
      float a2[4][4];
      #pragma unroll
      for(int i=0;i<4;i++){
        #pragma unroll
        for(int j=0;j<4;j++) a2[i][j]=0.f;
      }
      for(int kk=0;kk<128;kk++){
        float4 a=*(float4*)&sH[kk*68+m0b];
        float4 w=*(float4*)&sW2[kk*68+n0b];
        float av[4]={a.x,a.y,a.z,a.w}, wv[4]={w.x,w.y,w.z,w.w};
        #pragma unroll
        for(int i=0;i<4;i++){
          #pragma unroll
          for(int j=0;j<4;j++) a2[i][j]+=av[i]*wv[j];
        }
      }
      #pragma unroll
      for(int i=0;i<4;i++){
        float4 d;
        d.x=a2[i][0]+b2[nbase+n0b+0];
        d.y=a2[i][1]+b2[nbase+n0b+1];
        d.z=a2[i][2]+b2[nbase+n0b+2];
        d.w=a2[i][3]+b2[nbase+n0b+3];
        keacc += d.x*d.x+d.y*d.y+d.z*d.z+d.w*d.w;
        *(float4*)&out0[(tok0+m0b+i)*512 + nbase+n0b]=d;
      }
    } else {
      for(int i=tid;i<1024;i+=TPB){
        int m=i>>4, n4=(i&15)*4;
        float4 z={0.f,0.f,0.f,0.f};
        *(float4*)&out0[(tok0+m)*512 + nbase + n4]=z;
      }
    }
  }
  float tot=wave_reduce_sum(keacc);
  if((tid&63)==0) atomicAdd(&ke[b], 0.5f*tot);
}

// ---------------- launch ----------------
extern "C" void kernel_launch(void* const* d_in, const int* in_sizes, int n_in,
                              void* d_out, int out_size, void* d_ws, size_t ws_size,
                              hipStream_t stream)
{
  const float* y      = (const float*)d_in[1];
  const float* w1s[4] = {(const float*)d_in[3],(const float*)d_in[4],(const float*)d_in[5],(const float*)d_in[6]};
  const float* w2s[4] = {(const float*)d_in[7],(const float*)d_in[8],(const float*)d_in[9],(const float*)d_in[10]};
  const float* b2s[4] = {(const float*)d_in[11],(const float*)d_in[12],(const float*)d_in[13],(const float*)d_in[14]};
  const float* in_b1  = (const float*)d_in[15];
  const float* in_w2  = (const float*)d_in[16];
  const float* in_b2  = (const float*)d_in[17];
  const float* out_w1 = (const float*)d_in[18];
  const float* out_b1 = (const float*)d_in[19];
  const float* qkv_w  = (const float*)d_in[20];
  const float* qkv_b  = (const float*)d_in[21];
  const float* ao_w   = (const float*)d_in[22];
  const float* ao_b   = (const float*)d_in[23];
  const float* ln1w   = (const float*)d_in[24];
  const float* ln1b   = (const float*)d_in[25];
  const float* fw1    = (const float*)d_in[26];
  const float* fb1    = (const float*)d_in[27];
  const float* fw2    = (const float*)d_in[28];
  const float* fb2    = (const float*)d_in[29];
  const float* ln2w   = (const float*)d_in[30];
  const float* ln2b   = (const float*)d_in[31];

  float* out0 = (float*)d_out;
  float* keo  = out0 + (size_t)16*1024*512;

  float* X  = (float*)d_ws;                 // 16384 x 64
  float* T1 = X  + (size_t)16384*64;        // 16384 x 256 (qkv uses stride 192)
  float* O  = T1 + (size_t)16384*256;       // 16384 x 64

  k_in<<<256,TPB,0,stream>>>(y, w1s[0],w1s[1],w1s[2],w1s[3], in_b1, in_w2, in_b2, X);

  for(int l=0;l<2;l++){
    k_gemm<64,192,64,192,0,false><<<256,TPB,0,stream>>>(X, qkv_w + l*192*64, qkv_b + l*192, T1, nullptr,nullptr,nullptr);
    k_attn<<<256,TPB,0,stream>>>(T1, O);
    k_gemm<64,64,64,64,0,true><<<256,TPB,0,stream>>>(O, ao_w + l*64*64, ao_b + l*64, X, X, ln1w + l*64, ln1b + l*64);
    k_gemm<64,256,64,256,1,false><<<256,TPB,0,stream>>>(X, fw1 + l*256*64, fb1 + l*256, T1, nullptr,nullptr,nullptr);
    k_gemm<256,64,256,64,0,true><<<256,TPB,0,stream>>>(T1, fw2 + l*64*256, fb2 + l*64, X, X, ln2w + l*64, ln2b + l*64);
  }

  hipMemsetAsync(keo, 0, 16*sizeof(float), stream);
  k_out<<<256,TPB,0,stream>>>(X, out_w1, out_b1,
      w2s[0],w2s[1],w2s[2],w2s[3], b2s[0],b2s[1],b2s[2],b2s[3], out0, keo);
}

// Round 3
// 362.771 us; speedup vs baseline: 1.7833x; 1.4123x over previous
//
#include <hip/hip_runtime.h>
#include <math.h>

typedef short bf8v __attribute__((ext_vector_type(8)));
typedef float f4v  __attribute__((ext_vector_type(4)));

#define QS 0.36067376022224085f  // log2(e)/4

// ---- ws layout (ushort elements) ----
#define OFF_IN_W1  0        // per-seg {0,8192,24576,57344}, [128][F]
#define OFF_IN_W2  122880   // + seg*8192, [64][128]
#define OFF_OUT_W1 155648   // + seg*8192, [128][64]
#define OFF_OUT_W2 188416   // per-seg {0,8192,24576,57344}, [F][128]
#define OFF_QKV_W  311296   // + l*12288, [192][64] (Q rows pre-scaled by QS)
#define OFF_AO_W   335872   // + l*4096,  [64][64]
#define OFF_FW1    344064   // + l*16384, [256][64]
#define OFF_FW2    376832   // + l*16384, [64][256]
#define WTOT       409600
#define OFF_XA     409600
#define OFF_XB     (OFF_XA + 1048576)
#define OFF_OB     (OFF_XB + 1048576)
#define OFF_QKVB   (OFF_OB + 1048576)   // 16384*192

__device__ __forceinline__ ushort bf16_rne(float f){
  uint u = __float_as_uint(f);
  u += 0x7fffu + ((u>>16)&1u);
  return (ushort)(u>>16);
}
__device__ __forceinline__ float bf2f(uint u){ return __uint_as_float(u<<16); }
__device__ __forceinline__ uint2 pack4(const float v[4]){
  uint2 r;
  r.x = (uint)bf16_rne(v[0]) | ((uint)bf16_rne(v[1])<<16);
  r.y = (uint)bf16_rne(v[2]) | ((uint)bf16_rne(v[3])<<16);
  return r;
}
__device__ __forceinline__ void unpack4(uint2 p, float v[4]){
  v[0]=bf2f(p.x&0xffffu); v[1]=bf2f(p.x>>16); v[2]=bf2f(p.y&0xffffu); v[3]=bf2f(p.y>>16);
}
__device__ __forceinline__ float wave_reduce_sum(float v){
  #pragma unroll
  for(int o=32;o>0;o>>=1) v += __shfl_xor(v, o, 64);
  return v;
}
__device__ __forceinline__ int seg_w1off(int seg){
  return (seg==0)?0:(seg==1)?8192:(seg==2)?24576:57344;
}

// ---------------- weight bf16 conversion ----------------
__global__ __launch_bounds__(256) void k_prep(
    const float* __restrict__ iw10, const float* __restrict__ iw11,
    const float* __restrict__ iw12, const float* __restrict__ iw13,
    const float* __restrict__ iw2,  const float* __restrict__ ow1,
    const float* __restrict__ ow20, const float* __restrict__ ow21,
    const float* __restrict__ ow22, const float* __restrict__ ow23,
    const float* __restrict__ qkvw, const float* __restrict__ aow,
    const float* __restrict__ f1,   const float* __restrict__ f2,
    ushort* __restrict__ wb)
{
  const int stride = gridDim.x*256;
  for(int i = blockIdx.x*256 + threadIdx.x; i < WTOT; i += stride){
    float v; int j = i;
    if(j < 122880){
      if(j<8192) v=iw10[j];
      else if(j<24576) v=iw11[j-8192];
      else if(j<57344) v=iw12[j-24576];
      else v=iw13[j-57344];
    } else if(j < 155648) v = iw2[j-122880];
    else if(j < 188416) v = ow1[j-155648];
    else if(j < 311296){
      j -= 188416;
      if(j<8192) v=ow20[j];
      else if(j<24576) v=ow21[j-8192];
      else if(j<57344) v=ow22[j-24576];
      else v=ow23[j-57344];
    } else if(j < 335872){
      j -= 311296; v = qkvw[j];
      if(((j>>6)%192) < 64) v *= QS;     // pre-scale Q rows
    } else if(j < 344064) v = aow[j-335872];
    else if(j < 376832) v = f1[j-344064];
    else v = f2[j-376832];
    wb[i] = bf16_rne(v);
  }
}

// ---------------- zero-fill out0 padding ----------------
__global__ __launch_bounds__(256) void k_zero(float* __restrict__ out0){
  const int stride = gridDim.x*256;
  for(int i = blockIdx.x*256 + threadIdx.x; i < 16384*112; i += stride){
    int t = i/112, c = 64 + (i%112)*4;
    int F = 64 << ((t>>8)&3);
    if(c >= F){ float4 z={0,0,0,0}; *(float4*)&out0[(size_t)t*512 + c] = z; }
  }
}

// ---------------- input MLP ----------------
// 512 blocks x 32 tokens. GEMM1: A=in_w1 [128][F], B=y (fp32->bf16). tanh -> sH. GEMM2: A=in_w2 [64][128].
__global__ __launch_bounds__(256) void k_in(
    const float* __restrict__ y, const float* __restrict__ b1g, const float* __restrict__ b2g,
    const ushort* __restrict__ wb, ushort* __restrict__ X)
{
  __shared__ ushort sH[32*136];
  const int tid=threadIdx.x, lane=tid&63, w=tid>>6, ln=lane&15, quad=lane>>4;
  const int tok0=blockIdx.x*32;
  const int seg=(tok0>>8)&3, F=64<<seg;
  const ushort* W1 = wb + OFF_IN_W1 + seg_w1off(seg);
  const ushort* W2 = wb + OFF_IN_W2 + seg*8192;
  const float* b1 = b1g + seg*128;
  const float* b2 = b2g + seg*64;

  f4v acc[2][2];
  #pragma unroll
  for(int a=0;a<2;a++){ acc[a][0]=(f4v){0,0,0,0}; acc[a][1]=(f4v){0,0,0,0}; }
  const int nk = F>>5;
  for(int ks=0; ks<nk; ks++){
    const int kof = ks*32 + quad*8;
    bf8v bfr[2];
    #pragma unroll
    for(int j=0;j<2;j++){
      const float* yp = &y[(size_t)(tok0+j*16+ln)*512 + kof];
      float4 a = *(const float4*)yp;
      float4 c = *(const float4*)(yp+4);
      union{bf8v v; ushort s[8];} u;
      u.s[0]=bf16_rne(a.x); u.s[1]=bf16_rne(a.y); u.s[2]=bf16_rne(a.z); u.s[3]=bf16_rne(a.w);
      u.s[4]=bf16_rne(c.x); u.s[5]=bf16_rne(c.y); u.s[6]=bf16_rne(c.z); u.s[7]=bf16_rne(c.w);
      bfr[j]=u.v;
    }
    #pragma unroll
    for(int mf=0;mf<2;mf++){
      bf8v af = *(const bf8v*)&W1[(size_t)(w*32+mf*16+ln)*F + kof];
      acc[mf][0] = __builtin_amdgcn_mfma_f32_16x16x32_bf16(af, bfr[0], acc[mf][0], 0,0,0);
      acc[mf][1] = __builtin_amdgcn_mfma_f32_16x16x32_bf16(af, bfr[1], acc[mf][1], 0,0,0);
    }
  }
  #pragma unroll
  for(int mf=0;mf<2;mf++){
    const int f0 = w*32+mf*16+quad*4;
    float bb[4];
    #pragma unroll
    for(int r=0;r<4;r++) bb[r]=b1[f0+r];
    #pragma unroll
    for(int j=0;j<2;j++){
      float h[4];
      #pragma unroll
      for(int r=0;r<4;r++) h[r]=tanhf(acc[mf][j][r]+bb[r]);
      *(uint2*)&sH[(j*16+ln)*136 + f0] = pack4(h);
    }
  }
  __syncthreads();
  f4v a2[2] = {(f4v){0,0,0,0},(f4v){0,0,0,0}};
  #pragma unroll
  for(int ks=0;ks<4;ks++){
    const int kof = ks*32+quad*8;
    bf8v af = *(const bf8v*)&W2[(w*16+ln)*128 + kof];
    #pragma unroll
    for(int j=0;j<2;j++){
      bf8v bf = *(const bf8v*)&sH[(j*16+ln)*136 + kof];
      a2[j] = __builtin_amdgcn_mfma_f32_16x16x32_bf16(af, bf, a2[j], 0,0,0);
    }
  }
  const int f0 = w*16+quad*4;
  float bb[4];
  #pragma unroll
  for(int r=0;r<4;r++) bb[r]=b2[f0+r];
  #pragma unroll
  for(int j=0;j<2;j++){
    float o[4];
    #pragma unroll
    for(int r=0;r<4;r++) o[r]=a2[j][r]+bb[r];
    *(uint2*)&X[(size_t)(tok0+j*16+ln)*64 + f0] = pack4(o);
  }
}

// ---------------- QKV projection: no LDS, no barriers ----------------
__global__ __launch_bounds__(256) void k_qkv(
    const ushort* __restrict__ X, const ushort* __restrict__ Wq,
    const float* __restrict__ bq, ushort* __restrict__ QKV)
{
  const int tid=threadIdx.x, lane=tid&63, w=tid>>6, ln=lane&15, quad=lane>>4;
  const int tok0=blockIdx.x*32;
  const int fb = w*48;
  f4v acc[3][2];
  #pragma unroll
  for(int a=0;a<3;a++){ acc[a][0]=(f4v){0,0,0,0}; acc[a][1]=(f4v){0,0,0,0}; }
  #pragma unroll
  for(int ks=0;ks<2;ks++){
    const int kof = ks*32+quad*8;
    bf8v bf[2];
    #pragma unroll
    for(int j=0;j<2;j++) bf[j] = *(const bf8v*)&X[(size_t)(tok0+j*16+ln)*64 + kof];
    #pragma unroll
    for(int mf=0;mf<3;mf++){
      bf8v af = *(const bf8v*)&Wq[(fb+mf*16+ln)*64 + kof];
      acc[mf][0] = __builtin_amdgcn_mfma_f32_16x16x32_bf16(af, bf[0], acc[mf][0], 0,0,0);
      acc[mf][1] = __builtin_amdgcn_mfma_f32_16x16x32_bf16(af, bf[1], acc[mf][1], 0,0,0);
    }
  }
  #pragma unroll
  for(int mf=0;mf<3;mf++){
    const int f0 = fb+mf*16+quad*4;
    float bb[4];
    #pragma unroll
    for(int r=0;r<4;r++){ int f=f0+r; bb[r]=bq[f]*((f<64)?QS:1.f); }
    #pragma unroll
    for(int j=0;j<2;j++){
      float o[4];
      #pragma unroll
      for(int r=0;r<4;r++) o[r]=acc[mf][j][r]+bb[r];
      *(uint2*)&QKV[(size_t)(tok0+j*16+ln)*192 + f0] = pack4(o);
    }
  }
}

// ---------------- attention: bf16 MFMA, direct-global Q/K frags ----------------
// 512 blocks = 16b*4h*8qt; 4 waves x 32q each.
__global__ __launch_bounds__(256) void k_attn(const ushort* __restrict__ QKV, ushort* __restrict__ O)
{
  __shared__ ushort sV[16*72];
  __shared__ ushort sP[4][32*72];
  const int tid=threadIdx.x, lane=tid&63, w=tid>>6, ln=lane&15, quad=lane>>4;
  const int qt=blockIdx.x&7, h=(blockIdx.x>>3)&3, b=blockIdx.x>>5;
  const int rowQ0 = b*1024 + qt*128 + w*32;
  const int rowK0 = b*1024;

  const bf8v zf = {0,0,0,0,0,0,0,0};
  bf8v qf[2] = {zf, zf};
  if(quad<2){
    #pragma unroll
    for(int q2=0;q2<2;q2++)
      qf[q2] = *(const bf8v*)&QKV[(size_t)(rowQ0+q2*16+ln)*192 + h*16 + quad*8];
  }
  f4v oacc[2] = {(f4v){0,0,0,0},(f4v){0,0,0,0}};
  float lfull[2] = {0.f, 0.f};

  for(int kc=0;kc<16;kc++){
    __syncthreads();
    {
      const int t=tid>>2, dp=(tid&3)*4;
      uint2 vv = *(const uint2*)&QKV[(size_t)(rowK0+kc*64+t)*192 + 128 + h*16 + dp];
      sV[(dp+0)*72+t]=(ushort)(vv.x&0xffffu);
      sV[(dp+1)*72+t]=(ushort)(vv.x>>16);
      sV[(dp+2)*72+t]=(ushort)(vv.y&0xffffu);
      sV[(dp+3)*72+t]=(ushort)(vv.y>>16);
    }
    __syncthreads();
    ushort* Pw = sP[w];
    #pragma unroll
    for(int ks=0;ks<4;ks++){
      bf8v kf = zf;
      if(quad<2) kf = *(const bf8v*)&QKV[(size_t)(rowK0+kc*64+ks*16+ln)*192 + 64 + h*16 + quad*8];
      #pragma unroll
      for(int q2=0;q2<2;q2++){
        f4v st = __builtin_amdgcn_mfma_f32_16x16x32_bf16(kf, qf[q2], (f4v){0,0,0,0}, 0,0,0);
        float p[4];
        #pragma unroll
        for(int r=0;r<4;r++) p[r]=exp2f(st[r]);
        lfull[q2] += (p[0]+p[1])+(p[2]+p[3]);
        *(uint2*)&Pw[(q2*16+ln)*72 + ks*16+quad*4] = pack4(p);
      }
    }
    #pragma unroll
    for(int kh=0;kh<2;kh++){
      bf8v vf = *(const bf8v*)&sV[ln*72 + kh*32 + quad*8];
      #pragma unroll
      for(int q2=0;q2<2;q2++){
        bf8v pb = *(const bf8v*)&Pw[(q2*16+ln)*72 + kh*32 + quad*8];
        oacc[q2] = __builtin_amdgcn_mfma_f32_16x16x32_bf16(vf, pb, oacc[q2], 0,0,0);
      }
    }
  }
  #pragma unroll
  for(int q2=0;q2<2;q2++){
    float l = lfull[q2];
    l += __shfl_xor(l, 16, 64);
    l += __shfl_xor(l, 32, 64);
    float inv = __builtin_amdgcn_rcpf(l);
    float o[4];
    #pragma unroll
    for(int r=0;r<4;r++) o[r]=oacc[q2][r]*inv;
    *(uint2*)&O[(size_t)(rowQ0+q2*16+ln)*64 + h*16 + quad*4] = pack4(o);
  }
}

// ---------------- fused proj + LN1 + FFN1 + FFN2 + LN2 ----------------
// 512 blocks x 32 tokens; waves split features.
__global__ __launch_bounds__(256) void k_fused(
    const ushort* __restrict__ Xin, const ushort* __restrict__ Ob,
    const ushort* __restrict__ wb, int l,
    const float* __restrict__ aob, const float* __restrict__ l1wg, const float* __restrict__ l1bg,
    const float* __restrict__ fb1g, const float* __restrict__ fb2g,
    const float* __restrict__ l2wg, const float* __restrict__ l2bg,
    ushort* __restrict__ Xout)
{
  __shared__ ushort sX1[32*72];
  __shared__ ushort sH[32*264];
  __shared__ float2 sStat[32][4];
  const int tid=threadIdx.x, lane=tid&63, w=tid>>6, ln=lane&15, quad=lane>>4;
  const int tok0=blockIdx.x*32;
  const ushort* AO = wb + OFF_AO_W + l*4096;
  const ushort* W1 = wb + OFF_FW1  + l*16384;
  const ushort* W2 = wb + OFF_FW2  + l*16384;
  const int fs = w*16;

  // proj: A=AO [64][64], B=O
  f4v pa[2] = {(f4v){0,0,0,0},(f4v){0,0,0,0}};
  #pragma unroll
  for(int ks=0;ks<2;ks++){
    const int kof = ks*32+quad*8;
    bf8v af = *(const bf8v*)&AO[(fs+ln)*64 + kof];
    #pragma unroll
    for(int j=0;j<2;j++){
      bf8v bf = *(const bf8v*)&Ob[(size_t)(tok0+j*16+ln)*64 + kof];
      pa[j] = __builtin_amdgcn_mfma_f32_16x16x32_bf16(af, bf, pa[j], 0,0,0);
    }
  }
  float aob4[4], l1w[4], l1b[4], fb2v[4], l2w[4], l2b[4];
  #pragma unroll
  for(int r=0;r<4;r++){
    const int f = fs+quad*4+r;
    aob4[r]=aob[l*64+f]; l1w[r]=l1wg[l*64+f]; l1b[r]=l1bg[l*64+f];
    fb2v[r]=fb2g[l*64+f]; l2w[r]=l2wg[l*64+f]; l2b[r]=l2bg[l*64+f];
  }
  float v[2][4];
  #pragma unroll
  for(int j=0;j<2;j++){
    uint2 rx = *(const uint2*)&Xin[(size_t)(tok0+j*16+ln)*64 + fs+quad*4];
    float rr[4]; unpack4(rx, rr);
    #pragma unroll
    for(int r=0;r<4;r++) v[j][r]=pa[j][r]+aob4[r]+rr[r];
    float s1=(v[j][0]+v[j][1])+(v[j][2]+v[j][3]);
    float s2=(v[j][0]*v[j][0]+v[j][1]*v[j][1])+(v[j][2]*v[j][2]+v[j][3]*v[j][3]);
    s1 += __shfl_xor(s1,16,64); s1 += __shfl_xor(s1,32,64);
    s2 += __shfl_xor(s2,16,64); s2 += __shfl_xor(s2,32,64);
    if(quad==0) sStat[j*16+ln][w] = make_float2(s1,s2);
  }
  __syncthreads();
  float x1[2][4];
  #pragma unroll
  for(int j=0;j<2;j++){
    const int t=j*16+ln;
    float t1=0.f,t2=0.f;
    #pragma unroll
    for(int ww=0;ww<4;ww++){ float2 st=sStat[t][ww]; t1+=st.x; t2+=st.y; }
    float mean=t1*0.015625f, var=t2*0.015625f-mean*mean, rstd=rsqrtf(var+1e-5f);
    #pragma unroll
    for(int r=0;r<4;r++) x1[j][r]=(v[j][r]-mean)*rstd*l1w[r]+l1b[r];
    *(uint2*)&sX1[t*72 + fs+quad*4] = pack4(x1[j]);
  }
  __syncthreads();
  // FFN1: A=W1 [256][64]
  f4v f1a[4][2];
  #pragma unroll
  for(int a=0;a<4;a++){ f1a[a][0]=(f4v){0,0,0,0}; f1a[a][1]=(f4v){0,0,0,0}; }
  #pragma unroll
  for(int ks=0;ks<2;ks++){
    const int kof = ks*32+quad*8;
    bf8v bf[2];
    #pragma unroll
    for(int j=0;j<2;j++) bf[j] = *(const bf8v*)&sX1[(j*16+ln)*72 + kof];
    #pragma unroll
    for(int mf=0;mf<4;mf++){
      bf8v af = *(const bf8v*)&W1[(w*64+mf*16+ln)*64 + kof];
      f1a[mf][0] = __builtin_amdgcn_mfma_f32_16x16x32_bf16(af, bf[0], f1a[mf][0], 0,0,0);
      f1a[mf][1] = __builtin_amdgcn_mfma_f32_16x16x32_bf16(af, bf[1], f1a[mf][1], 0,0,0);
    }
  }
  #pragma unroll
  for(int mf=0;mf<4;mf++){
    const int f0 = w*64+mf*16+quad*4;
    float bb[4];
    #pragma unroll
    for(int r=0;r<4;r++) bb[r]=fb1g[l*256+f0+r];
    #pragma unroll
    for(int j=0;j<2;j++){
      float hh[4];
      #pragma unroll
      for(int r=0;r<4;r++) hh[r]=fmaxf(f1a[mf][j][r]+bb[r],0.f);
      *(uint2*)&sH[(j*16+ln)*264 + f0] = pack4(hh);
    }
  }
  __syncthreads();
  // FFN2: A=W2 [64][256]
  f4v f2a[2] = {(f4v){0,0,0,0},(f4v){0,0,0,0}};
  #pragma unroll
  for(int ks=0;ks<8;ks++){
    const int kof = ks*32+quad*8;
    bf8v af = *(const bf8v*)&W2[(fs+ln)*256 + kof];
    #pragma unroll
    for(int j=0;j<2;j++){
      bf8v bf = *(const bf8v*)&sH[(j*16+ln)*264 + kof];
      f2a[j] = __builtin_amdgcn_mfma_f32_16x16x32_bf16(af, bf, f2a[j], 0,0,0);
    }
  }
  float v2[2][4];
  #pragma unroll
  for(int j=0;j<2;j++){
    #pragma unroll
    for(int r=0;r<4;r++) v2[j][r]=f2a[j][r]+fb2v[r]+x1[j][r];
    float s1=(v2[j][0]+v2[j][1])+(v2[j][2]+v2[j][3]);
    float s2=(v2[j][0]*v2[j][0]+v2[j][1]*v2[j][1])+(v2[j][2]*v2[j][2]+v2[j][3]*v2[j][3]);
    s1 += __shfl_xor(s1,16,64); s1 += __shfl_xor(s1,32,64);
    s2 += __shfl_xor(s2,16,64); s2 += __shfl_xor(s2,32,64);
    if(quad==0) sStat[j*16+ln][w] = make_float2(s1,s2);
  }
  __syncthreads();
  #pragma unroll
  for(int j=0;j<2;j++){
    const int t=j*16+ln;
    float t1=0.f,t2=0.f;
    #pragma unroll
    for(int ww=0;ww<4;ww++){ float2 st=sStat[t][ww]; t1+=st.x; t2+=st.y; }
    float mean=t1*0.015625f, var=t2*0.015625f-mean*mean, rstd=rsqrtf(var+1e-5f);
    float xo[4];
    #pragma unroll
    for(int r=0;r<4;r++) xo[r]=(v2[j][r]-mean)*rstd*l2w[r]+l2b[r];
    *(uint2*)&Xout[(size_t)(tok0+t)*64 + fs+quad*4] = pack4(xo);
  }
}

// ---------------- output head + ke ----------------
// 960 blocks: seg0:64, seg1:128, seg2:256, seg3:512 (tok-block x n-chunk)
__global__ __launch_bounds__(256) void k_out(
    const ushort* __restrict__ X, const ushort* __restrict__ wb,
    const float* __restrict__ ob1g,
    const float* __restrict__ b20, const float* __restrict__ b21,
    const float* __restrict__ b22, const float* __restrict__ b23,
    float* __restrict__ out0, float* __restrict__ ke)
{
  __shared__ ushort sH[64*136];
  const int tid=threadIdx.x, lane=tid&63, w=tid>>6, ln=lane&15, quad=lane>>4;
  const int bid=blockIdx.x;
  int seg, tb, ch;
  if(bid<64){ seg=0; tb=bid; ch=0; }
  else if(bid<192){ seg=1; int r=bid-64; tb=r>>1; ch=r&1; }
  else if(bid<448){ seg=2; int r=bid-192; tb=r>>2; ch=r&3; }
  else { seg=3; int r=bid-448; tb=r>>3; ch=r&7; }
  const int b = tb>>2;
  const int tok0 = b*1024 + seg*256 + (tb&3)*64;
  const ushort* W1 = wb + OFF_OUT_W1 + seg*8192;          // [128][64]
  const ushort* W2 = wb + OFF_OUT_W2 + seg_w1off(seg) + (size_t)(ch*64)*128; // [64][128]
  const float* b1 = ob1g + seg*128;
  const float* b2 = (seg==0?b20: seg==1?b21: seg==2?b22: b23) + ch*64;

  f4v a1[2][4];
  #pragma unroll
  for(int a=0;a<2;a++)
    #pragma unroll
    for(int j=0;j<4;j++) a1[a][j]=(f4v){0,0,0,0};
  #pragma unroll
  for(int ks=0;ks<2;ks++){
    const int kof = ks*32+quad*8;
    bf8v bf[4];
    #pragma unroll
    for(int j=0;j<4;j++) bf[j] = *(const bf8v*)&X[(size_t)(tok0+j*16+ln)*64 + kof];
    #pragma unroll
    for(int mf=0;mf<2;mf++){
      bf8v af = *(const bf8v*)&W1[(w*32+mf*16+ln)*64 + kof];
      #pragma unroll
      for(int j=0;j<4;j++) a1[mf][j]=__builtin_amdgcn_mfma_f32_16x16x32_bf16(af, bf[j], a1[mf][j], 0,0,0);
    }
  }
  #pragma unroll
  for(int mf=0;mf<2;mf++){
    const int f0 = w*32+mf*16+quad*4;
    float bb[4];
    #pragma unroll
    for(int r=0;r<4;r++) bb[r]=b1[f0+r];
    #pragma unroll
    for(int j=0;j<4;j++){
      float hh[4];
      #pragma unroll
      for(int r=0;r<4;r++) hh[r]=tanhf(a1[mf][j][r]+bb[r]);
      *(uint2*)&sH[(j*16+ln)*136 + f0] = pack4(hh);
    }
  }
  __syncthreads();
  f4v a2[4];
  #pragma unroll
  for(int j=0;j<4;j++) a2[j]=(f4v){0,0,0,0};
  #pragma unroll
  for(int ks=0;ks<4;ks++){
    const int kof = ks*32+quad*8;
    bf8v af = *(const bf8v*)&W2[(w*16+ln)*128 + kof];
    #pragma unroll
    for(int j=0;j<4;j++){
      bf8v bf = *(const bf8v*)&sH[(j*16+ln)*136 + kof];
      a2[j]=__builtin_amdgcn_mfma_f32_16x16x32_bf16(af, bf, a2[j], 0,0,0);
    }
  }
  const int f0 = w*16+quad*4;
  float bb[4];
  #pragma unroll
  for(int r=0;r<4;r++) bb[r]=b2[f0+r];
  float keacc=0.f;
  #pragma unroll
  for(int j=0;j<4;j++){
    float d[4];
    #pragma unroll
    for(int r=0;r<4;r++){ d[r]=a2[j][r]+bb[r]; keacc+=d[r]*d[r]; }
    float4 o = {d[0],d[1],d[2],d[3]};
    *(float4*)&out0[(size_t)(tok0+j*16+ln)*512 + ch*64 + f0] = o;
  }
  float tot = wave_reduce_sum(keacc);
  if(lane==0) atomicAdd(&ke[b], 0.5f*tot);
}

// ---------------- launch ----------------
extern "C" void kernel_launch(void* const* d_in, const int* in_sizes, int n_in,
                              void* d_out, int out_size, void* d_ws, size_t ws_size,
                              hipStream_t stream)
{
  const float* y      = (const float*)d_in[1];
  const float* w1s[4] = {(const float*)d_in[3],(const float*)d_in[4],(const float*)d_in[5],(const float*)d_in[6]};
  const float* w2s[4] = {(const float*)d_in[7],(const float*)d_in[8],(const float*)d_in[9],(const float*)d_in[10]};
  const float* b2s[4] = {(const float*)d_in[11],(const float*)d_in[12],(const float*)d_in[13],(const float*)d_in[14]};
  const float* in_b1  = (const float*)d_in[15];
  const float* in_w2  = (const float*)d_in[16];
  const float* in_b2  = (const float*)d_in[17];
  const float* out_w1 = (const float*)d_in[18];
  const float* out_b1 = (const float*)d_in[19];
  const float* qkv_w  = (const float*)d_in[20];
  const float* qkv_b  = (const float*)d_in[21];
  const float* ao_w   = (const float*)d_in[22];
  const float* ao_b   = (const float*)d_in[23];
  const float* ln1w   = (const float*)d_in[24];
  const float* ln1b   = (const float*)d_in[25];
  const float* fw1    = (const float*)d_in[26];
  const float* fb1    = (const float*)d_in[27];
  const float* fw2    = (const float*)d_in[28];
  const float* fb2    = (const float*)d_in[29];
  const float* ln2w   = (const float*)d_in[30];
  const float* ln2b   = (const float*)d_in[31];

  float* out0 = (float*)d_out;
  float* keo  = out0 + (size_t)16*1024*512;

  ushort* wb   = (ushort*)d_ws;
  ushort* XA   = wb + OFF_XA;
  ushort* XB   = wb + OFF_XB;
  ushort* OB   = wb + OFF_OB;
  ushort* QKVB = wb + OFF_QKVB;

  k_prep<<<512,256,0,stream>>>(w1s[0],w1s[1],w1s[2],w1s[3], in_w2, out_w1,
      w2s[0],w2s[1],w2s[2],w2s[3], qkv_w, ao_w, fw1, fw2, wb);
  k_zero<<<2048,256,0,stream>>>(out0);
  hipMemsetAsync(keo, 0, 16*sizeof(float), stream);

  k_in<<<512,256,0,stream>>>(y, in_b1, in_b2, wb, XA);

  for(int l=0;l<2;l++){
    const ushort* Xc = l ? XB : XA;
    ushort*       Xn = l ? XA : XB;
    k_qkv<<<512,256,0,stream>>>(Xc, wb + OFF_QKV_W + l*12288, qkv_b + l*192, QKVB);
    k_attn<<<512,256,0,stream>>>(QKVB, OB);
    k_fused<<<512,256,0,stream>>>(Xc, OB, wb, l, ao_b, ln1w, ln1b, fb1, fb2, ln2w, ln2b, Xn);
  }

  k_out<<<960,256,0,stream>>>(XA, wb, out_b1, b2s[0],b2s[1],b2s[2],b2s[3], out0, keo);
}

// Round 4
// 311.576 us; speedup vs baseline: 2.0763x; 1.1643x over previous
//
#include <hip/hip_runtime.h>
#include <math.h>

typedef short bf8v __attribute__((ext_vector_type(8)));
typedef float f4v  __attribute__((ext_vector_type(4)));

#define QS 0.36067376022224085f  // log2(e)/4

// ---- ws layout (ushort units) ----
#define OFF_IN_W1  0        // per-seg {0,8192,24576,57344}, [128][F]
#define OFF_IN_W2  122880   // + seg*8192, [64][128]
#define OFF_OUT_W1 155648   // + seg*8192, [128][64]
#define OFF_OUT_W2 188416   // per-seg {0,8192,24576,57344}, [F][128]
#define OFF_QKV_W  311296   // + l*12288, [192][64] (Q rows pre-scaled by QS)
#define OFF_AO_W   335872   // + l*4096,  [64][64]
#define OFF_FW1    344064   // + l*16384, [256][64]
#define OFF_FW2    376832   // + l*16384, [64][256]
#define WTOT       409600
#define OFF_XA     409600
#define OFF_XB     1458176
#define OFF_OB     2506752
#define OFF_QKB    3555328  // [tok][128]: Q@0 (prescaled), K@64
#define OFF_VT     5652480  // [b][h][d16][1024] bf16
#define OFF_KE     6701056  // 1024 floats (block partials)

__device__ __forceinline__ ushort bf16_rne(float f){
  uint u = __float_as_uint(f);
  u += 0x7fffu + ((u>>16)&1u);
  return (ushort)(u>>16);
}
__device__ __forceinline__ float bf2f(uint u){ return __uint_as_float(u<<16); }
__device__ __forceinline__ uint2 pack4(const float v[4]){
  uint2 r;
  r.x = (uint)bf16_rne(v[0]) | ((uint)bf16_rne(v[1])<<16);
  r.y = (uint)bf16_rne(v[2]) | ((uint)bf16_rne(v[3])<<16);
  return r;
}
__device__ __forceinline__ void unpack4(uint2 p, float v[4]){
  v[0]=bf2f(p.x&0xffffu); v[1]=bf2f(p.x>>16); v[2]=bf2f(p.y&0xffffu); v[3]=bf2f(p.y>>16);
}
__device__ __forceinline__ float wave_reduce_sum(float v){
  #pragma unroll
  for(int o=32;o>0;o>>=1) v += __shfl_xor(v, o, 64);
  return v;
}
__device__ __forceinline__ float fast_tanh(float x){
  float t = exp2f(2.8853900817779268f*x);   // exp(2x)
  return (t-1.f)*__builtin_amdgcn_rcpf(t+1.f);
}
__device__ __forceinline__ int seg_w1off(int seg){
  return (seg==0)?0:(seg==1)?8192:(seg==2)?24576:57344;
}

// ---------------- setup: weight bf16 conversion + out0 padding zero ----------------
__global__ __launch_bounds__(256) void k_setup(
    const float* __restrict__ iw10, const float* __restrict__ iw11,
    const float* __restrict__ iw12, const float* __restrict__ iw13,
    const float* __restrict__ iw2,  const float* __restrict__ ow1,
    const float* __restrict__ ow20, const float* __restrict__ ow21,
    const float* __restrict__ ow22, const float* __restrict__ ow23,
    const float* __restrict__ qkvw, const float* __restrict__ aow,
    const float* __restrict__ f1,   const float* __restrict__ f2,
    ushort* __restrict__ wb, float* __restrict__ out0)
{
  const int tid = threadIdx.x;
  const int stride = 512*256;
  if(blockIdx.x < 512){
    for(int i = blockIdx.x*256 + tid; i < WTOT; i += stride){
      float v; int j = i;
      if(j < 122880){
        if(j<8192) v=iw10[j];
        else if(j<24576) v=iw11[j-8192];
        else if(j<57344) v=iw12[j-24576];
        else v=iw13[j-57344];
      } else if(j < 155648) v = iw2[j-122880];
      else if(j < 188416) v = ow1[j-155648];
      else if(j < 311296){
        j -= 188416;
        if(j<8192) v=ow20[j];
        else if(j<24576) v=ow21[j-8192];
        else if(j<57344) v=ow22[j-24576];
        else v=ow23[j-57344];
      } else if(j < 335872){
        j -= 311296; v = qkvw[j];
        if(((j>>6)%192) < 64) v *= QS;
      } else if(j < 344064) v = aow[j-335872];
      else if(j < 376832) v = f1[j-344064];
      else v = f2[j-376832];
      wb[i] = bf16_rne(v);
    }
  } else {
    for(int i = (blockIdx.x-512)*256 + tid; i < 16384*112; i += stride){
      int t = i/112, c = 64 + (i%112)*4;
      int F = 64 << ((t>>8)&3);
      if(c >= F){ float4 z={0,0,0,0}; *(float4*)&out0[(size_t)t*512 + c] = z; }
    }
  }
}

// ---------------- input MLP + QKV(l=0): 1024 blocks x 1 wave x 16 tokens ----------------
__global__ __launch_bounds__(64) void k_in(
    const float* __restrict__ y, const float* __restrict__ b1g, const float* __restrict__ b2g,
    const float* __restrict__ bqg, const ushort* __restrict__ wb,
    ushort* __restrict__ X, ushort* __restrict__ QKB, ushort* __restrict__ VT)
{
  __shared__ ushort sH[16*136];
  __shared__ ushort sX[16*72];
  const int lane=threadIdx.x, ln=lane&15, quad=lane>>4;
  const int tok0=blockIdx.x*16;
  const int seg=(tok0>>8)&3, F=64<<seg, b=tok0>>10;
  const ushort* W1 = wb + OFF_IN_W1 + seg_w1off(seg);
  const ushort* W2 = wb + OFF_IN_W2 + seg*8192;
  const ushort* Wq = wb + OFF_QKV_W;                 // layer 0
  const float* b1 = b1g + seg*128;
  const float* b2 = b2g + seg*64;

  // GEMM1: A=in_w1 [128][F], B=y tokens
  f4v a1[8];
  #pragma unroll
  for(int m=0;m<8;m++) a1[m]=(f4v){0,0,0,0};
  const int nk = F>>5;
  for(int ks=0; ks<nk; ks++){
    const int kof = ks*32 + quad*8;
    const float* yp = &y[(size_t)(tok0+ln)*512 + kof];
    float4 a = *(const float4*)yp;
    float4 c = *(const float4*)(yp+4);
    union{bf8v v; ushort s[8];} u;
    u.s[0]=bf16_rne(a.x); u.s[1]=bf16_rne(a.y); u.s[2]=bf16_rne(a.z); u.s[3]=bf16_rne(a.w);
    u.s[4]=bf16_rne(c.x); u.s[5]=bf16_rne(c.y); u.s[6]=bf16_rne(c.z); u.s[7]=bf16_rne(c.w);
    #pragma unroll
    for(int mf=0;mf<8;mf++){
      bf8v af = *(const bf8v*)&W1[(size_t)(mf*16+ln)*F + kof];
      a1[mf] = __builtin_amdgcn_mfma_f32_16x16x32_bf16(af, u.v, a1[mf], 0,0,0);
    }
  }
  #pragma unroll
  for(int mf=0;mf<8;mf++){
    float4 bb = *(const float4*)&b1[mf*16+quad*4];
    float h[4] = { fast_tanh(a1[mf][0]+bb.x), fast_tanh(a1[mf][1]+bb.y),
                   fast_tanh(a1[mf][2]+bb.z), fast_tanh(a1[mf][3]+bb.w) };
    *(uint2*)&sH[ln*136 + mf*16+quad*4] = pack4(h);
  }
  // GEMM2: A=in_w2 [64][128] (same-wave LDS RAW, no barrier)
  f4v a2[4];
  #pragma unroll
  for(int m=0;m<4;m++) a2[m]=(f4v){0,0,0,0};
  #pragma unroll
  for(int ks=0;ks<4;ks++){
    const int kof = ks*32+quad*8;
    bf8v bfh = *(const bf8v*)&sH[ln*136 + kof];
    #pragma unroll
    for(int mf=0;mf<4;mf++){
      bf8v af = *(const bf8v*)&W2[(mf*16+ln)*128 + kof];
      a2[mf] = __builtin_amdgcn_mfma_f32_16x16x32_bf16(af, bfh, a2[mf], 0,0,0);
    }
  }
  #pragma unroll
  for(int mf=0;mf<4;mf++){
    float4 bb = *(const float4*)&b2[mf*16+quad*4];
    float o[4] = { a2[mf][0]+bb.x, a2[mf][1]+bb.y, a2[mf][2]+bb.z, a2[mf][3]+bb.w };
    uint2 u = pack4(o);
    *(uint2*)&X[(size_t)(tok0+ln)*64 + mf*16+quad*4] = u;
    *(uint2*)&sX[ln*72 + mf*16+quad*4] = u;
  }
  // QKV tail (layer 0)
  f4v aq[12];
  #pragma unroll
  for(int m=0;m<12;m++) aq[m]=(f4v){0,0,0,0};
  #pragma unroll
  for(int ks=0;ks<2;ks++){
    const int kof = ks*32+quad*8;
    bf8v bfx = *(const bf8v*)&sX[ln*72 + kof];
    #pragma unroll
    for(int mf=0;mf<12;mf++){
      bf8v af = *(const bf8v*)&Wq[(mf*16+ln)*64 + kof];
      aq[mf] = __builtin_amdgcn_mfma_f32_16x16x32_bf16(af, bfx, aq[mf], 0,0,0);
    }
  }
  #pragma unroll
  for(int mf=0;mf<8;mf++){
    const int f0 = mf*16+quad*4;
    float4 bb = *(const float4*)&bqg[f0];
    const float s = (mf<4)?QS:1.f;
    float o[4] = { aq[mf][0]+bb.x*s, aq[mf][1]+bb.y*s, aq[mf][2]+bb.z*s, aq[mf][3]+bb.w*s };
    *(uint2*)&QKB[(size_t)(tok0+ln)*128 + f0] = pack4(o);
  }
  #pragma unroll
  for(int mf=8;mf<12;mf++){
    const int h = mf-8;
    float4 bb = *(const float4*)&bqg[128 + h*16 + quad*4];
    float bv[4]={bb.x,bb.y,bb.z,bb.w};
    #pragma unroll
    for(int r=0;r<4;r++)
      VT[(size_t)((b*4+h)*16 + quad*4+r)*1024 + tok0+ln] = bf16_rne(aq[mf][r]+bv[r]);
  }
}

// ---------------- attention: 2048 blocks x 1 wave x 32 q ----------------
__global__ __launch_bounds__(64) void k_attn(
    const ushort* __restrict__ QKB, const ushort* __restrict__ VT, ushort* __restrict__ O)
{
  __shared__ ushort sP[32*72];
  const int lane=threadIdx.x, ln=lane&15, quad=lane>>4;
  const int qb=blockIdx.x&31, h=(blockIdx.x>>5)&3, b=blockIdx.x>>7;
  const int rowQ0 = b*1024 + qb*32;
  const int rowK0 = b*1024;
  const ushort* VTh = VT + (size_t)((b*4+h)*16)*1024;

  const bf8v zf = {0,0,0,0,0,0,0,0};
  bf8v qf[2] = {zf, zf};
  if(quad<2){
    #pragma unroll
    for(int q2=0;q2<2;q2++)
      qf[q2] = *(const bf8v*)&QKB[(size_t)(rowQ0+q2*16+ln)*128 + h*16 + quad*8];
  }
  f4v oacc[2] = {(f4v){0,0,0,0},(f4v){0,0,0,0}};
  float lfull[2] = {0.f,0.f};

  for(int kc=0;kc<16;kc++){
    #pragma unroll
    for(int ks=0;ks<4;ks++){
      bf8v kf = zf;
      if(quad<2) kf = *(const bf8v*)&QKB[(size_t)(rowK0+kc*64+ks*16+ln)*128 + 64 + h*16 + quad*8];
      #pragma unroll
      for(int q2=0;q2<2;q2++){
        f4v st = __builtin_amdgcn_mfma_f32_16x16x32_bf16(kf, qf[q2], (f4v){0,0,0,0}, 0,0,0);
        float p[4];
        #pragma unroll
        for(int r=0;r<4;r++) p[r]=exp2f(st[r]);
        lfull[q2] += (p[0]+p[1])+(p[2]+p[3]);
        *(uint2*)&sP[(q2*16+ln)*72 + ks*16+quad*4] = pack4(p);
      }
    }
    #pragma unroll
    for(int kh=0;kh<2;kh++){
      bf8v vf = *(const bf8v*)&VTh[(size_t)ln*1024 + kc*64 + kh*32 + quad*8];
      #pragma unroll
      for(int q2=0;q2<2;q2++){
        bf8v pa = *(const bf8v*)&sP[(q2*16+ln)*72 + kh*32 + quad*8];
        oacc[q2] = __builtin_amdgcn_mfma_f32_16x16x32_bf16(pa, vf, oacc[q2], 0,0,0);
      }
    }
  }
  #pragma unroll
  for(int q2=0;q2<2;q2++){
    float l = lfull[q2];
    l += __shfl_xor(l, 16, 64);
    l += __shfl_xor(l, 32, 64);
    #pragma unroll
    for(int r=0;r<4;r++){
      float lr = __shfl(l, quad*4+r, 64);
      float ov = oacc[q2][r]*__builtin_amdgcn_rcpf(lr);
      O[(size_t)(rowQ0+q2*16+quad*4+r)*64 + h*16 + ln] = bf16_rne(ov);
    }
  }
}

// ---------------- fused proj+LN1+FFN1+FFN2+LN2 (+QKV next): 1024 blocks x 1 wave x 16 tok ----------------
template<bool DOQ>
__global__ __launch_bounds__(64) void k_fused(
    const ushort* __restrict__ Xin, const ushort* __restrict__ Ob,
    const ushort* __restrict__ wb, int l,
    const float* __restrict__ aob, const float* __restrict__ l1wg, const float* __restrict__ l1bg,
    const float* __restrict__ fb1g, const float* __restrict__ fb2g,
    const float* __restrict__ l2wg, const float* __restrict__ l2bg,
    ushort* __restrict__ Xout, ushort* __restrict__ QKB, ushort* __restrict__ VT,
    const float* __restrict__ bqn)
{
  __shared__ ushort sX[16*72];
  __shared__ ushort sH[16*264];
  const int lane=threadIdx.x, ln=lane&15, quad=lane>>4;
  const int tok0=blockIdx.x*16, b=tok0>>10;
  const ushort* AO = wb + OFF_AO_W + l*4096;
  const ushort* W1 = wb + OFF_FW1  + l*16384;
  const ushort* W2 = wb + OFF_FW2  + l*16384;

  // proj: A=AO [64][64], B=O tokens
  f4v pa[4];
  #pragma unroll
  for(int m=0;m<4;m++) pa[m]=(f4v){0,0,0,0};
  #pragma unroll
  for(int ks=0;ks<2;ks++){
    const int kof = ks*32+quad*8;
    bf8v bfo = *(const bf8v*)&Ob[(size_t)(tok0+ln)*64 + kof];
    #pragma unroll
    for(int mf=0;mf<4;mf++){
      bf8v af = *(const bf8v*)&AO[(mf*16+ln)*64 + kof];
      pa[mf] = __builtin_amdgcn_mfma_f32_16x16x32_bf16(af, bfo, pa[mf], 0,0,0);
    }
  }
  float v1[4][4]; float s1=0.f, s2=0.f;
  #pragma unroll
  for(int mf=0;mf<4;mf++){
    float4 ab = *(const float4*)&aob[l*64 + mf*16+quad*4];
    float av[4]={ab.x,ab.y,ab.z,ab.w};
    uint2 rx = *(const uint2*)&Xin[(size_t)(tok0+ln)*64 + mf*16+quad*4];
    float rr[4]; unpack4(rx, rr);
    #pragma unroll
    for(int r=0;r<4;r++){ float t=pa[mf][r]+av[r]+rr[r]; v1[mf][r]=t; s1+=t; s2+=t*t; }
  }
  s1 += __shfl_xor(s1,16,64); s1 += __shfl_xor(s1,32,64);
  s2 += __shfl_xor(s2,16,64); s2 += __shfl_xor(s2,32,64);
  float mean = s1*0.015625f, var = s2*0.015625f - mean*mean, rstd = rsqrtf(var+1e-5f);
  float x1[4][4];
  #pragma unroll
  for(int mf=0;mf<4;mf++){
    float4 lw = *(const float4*)&l1wg[l*64 + mf*16+quad*4];
    float4 lb = *(const float4*)&l1bg[l*64 + mf*16+quad*4];
    float wv[4]={lw.x,lw.y,lw.z,lw.w}, bv[4]={lb.x,lb.y,lb.z,lb.w};
    #pragma unroll
    for(int r=0;r<4;r++) x1[mf][r]=(v1[mf][r]-mean)*rstd*wv[r]+bv[r];
    *(uint2*)&sX[ln*72 + mf*16+quad*4] = pack4(x1[mf]);
  }
  // FFN1: A=W1 [256][64]
  f4v f1[16];
  #pragma unroll
  for(int m=0;m<16;m++) f1[m]=(f4v){0,0,0,0};
  #pragma unroll
  for(int ks=0;ks<2;ks++){
    const int kof = ks*32+quad*8;
    bf8v bfx = *(const bf8v*)&sX[ln*72 + kof];
    #pragma unroll
    for(int mf=0;mf<16;mf++){
      bf8v af = *(const bf8v*)&W1[(mf*16+ln)*64 + kof];
      f1[mf] = __builtin_amdgcn_mfma_f32_16x16x32_bf16(af, bfx, f1[mf], 0,0,0);
    }
  }
  #pragma unroll
  for(int mf=0;mf<16;mf++){
    float4 bb = *(const float4*)&fb1g[l*256 + mf*16+quad*4];
    float h[4] = { fmaxf(f1[mf][0]+bb.x,0.f), fmaxf(f1[mf][1]+bb.y,0.f),
                   fmaxf(f1[mf][2]+bb.z,0.f), fmaxf(f1[mf][3]+bb.w,0.f) };
    *(uint2*)&sH[ln*264 + mf*16+quad*4] = pack4(h);
  }
  // FFN2: A=W2 [64][256]
  f4v f2[4];
  #pragma unroll
  for(int m=0;m<4;m++) f2[m]=(f4v){0,0,0,0};
  #pragma unroll
  for(int ks=0;ks<8;ks++){
    const int kof = ks*32+quad*8;
    bf8v bfh = *(const bf8v*)&sH[ln*264 + kof];
    #pragma unroll
    for(int mf=0;mf<4;mf++){
      bf8v af = *(const bf8v*)&W2[(mf*16+ln)*256 + kof];
      f2[mf] = __builtin_amdgcn_mfma_f32_16x16x32_bf16(af, bfh, f2[mf], 0,0,0);
    }
  }
  float v2[4][4]; s1=0.f; s2=0.f;
  #pragma unroll
  for(int mf=0;mf<4;mf++){
    float4 bb = *(const float4*)&fb2g[l*64 + mf*16+quad*4];
    float bv[4]={bb.x,bb.y,bb.z,bb.w};
    #pragma unroll
    for(int r=0;r<4;r++){ float t=f2[mf][r]+bv[r]+x1[mf][r]; v2[mf][r]=t; s1+=t; s2+=t*t; }
  }
  s1 += __shfl_xor(s1,16,64); s1 += __shfl_xor(s1,32,64);
  s2 += __shfl_xor(s2,16,64); s2 += __shfl_xor(s2,32,64);
  mean = s1*0.015625f; var = s2*0.015625f - mean*mean; rstd = rsqrtf(var+1e-5f);
  #pragma unroll
  for(int mf=0;mf<4;mf++){
    float4 lw = *(const float4*)&l2wg[l*64 + mf*16+quad*4];
    float4 lb = *(const float4*)&l2bg[l*64 + mf*16+quad*4];
    float wv[4]={lw.x,lw.y,lw.z,lw.w}, bv[4]={lb.x,lb.y,lb.z,lb.w};
    float xo[4];
    #pragma unroll
    for(int r=0;r<4;r++) xo[r]=(v2[mf][r]-mean)*rstd*wv[r]+bv[r];
    uint2 u = pack4(xo);
    *(uint2*)&Xout[(size_t)(tok0+ln)*64 + mf*16+quad*4] = u;
    if(DOQ) *(uint2*)&sX[ln*72 + mf*16+quad*4] = u;
  }
  if(DOQ){
    const ushort* Wq = wb + OFF_QKV_W + (l+1)*12288;
    f4v aq[12];
    #pragma unroll
    for(int m=0;m<12;m++) aq[m]=(f4v){0,0,0,0};
    #pragma unroll
    for(int ks=0;ks<2;ks++){
      const int kof = ks*32+quad*8;
      bf8v bfx = *(const bf8v*)&sX[ln*72 + kof];
      #pragma unroll
      for(int mf=0;mf<12;mf++){
        bf8v af = *(const bf8v*)&Wq[(mf*16+ln)*64 + kof];
        aq[mf] = __builtin_amdgcn_mfma_f32_16x16x32_bf16(af, bfx, aq[mf], 0,0,0);
      }
    }
    const float* bq = bqn + (l+1)*192;
    #pragma unroll
    for(int mf=0;mf<8;mf++){
      const int f0 = mf*16+quad*4;
      float4 bb = *(const float4*)&bq[f0];
      const float s = (mf<4)?QS:1.f;
      float o[4] = { aq[mf][0]+bb.x*s, aq[mf][1]+bb.y*s, aq[mf][2]+bb.z*s, aq[mf][3]+bb.w*s };
      *(uint2*)&QKB[(size_t)(tok0+ln)*128 + f0] = pack4(o);
    }
    #pragma unroll
    for(int mf=8;mf<12;mf++){
      const int h = mf-8;
      float4 bb = *(const float4*)&bq[128 + h*16 + quad*4];
      float bv[4]={bb.x,bb.y,bb.z,bb.w};
      #pragma unroll
      for(int r=0;r<4;r++)
        VT[(size_t)((b*4+h)*16 + quad*4+r)*1024 + tok0+ln] = bf16_rne(aq[mf][r]+bv[r]);
    }
  }
}

// ---------------- output head: 1024 blocks x 1 wave x 16 tokens (all chunks) ----------------
__global__ __launch_bounds__(64) void k_out(
    const ushort* __restrict__ X, const ushort* __restrict__ wb,
    const float* __restrict__ ob1g,
    const float* __restrict__ b20, const float* __restrict__ b21,
    const float* __restrict__ b22, const float* __restrict__ b23,
    float* __restrict__ out0, float* __restrict__ slots)
{
  __shared__ ushort sH[16*136];
  const int lane=threadIdx.x, ln=lane&15, quad=lane>>4;
  const int tok0=blockIdx.x*16;
  const int seg=(tok0>>8)&3, F=64<<seg;
  const ushort* W1 = wb + OFF_OUT_W1 + seg*8192;         // [128][64]
  const ushort* W2 = wb + OFF_OUT_W2 + seg_w1off(seg);   // [F][128]
  const float* b1 = ob1g + seg*128;
  const float* b2 = seg==0?b20: seg==1?b21: seg==2?b22: b23;

  f4v a1[8];
  #pragma unroll
  for(int m=0;m<8;m++) a1[m]=(f4v){0,0,0,0};
  #pragma unroll
  for(int ks=0;ks<2;ks++){
    const int kof = ks*32+quad*8;
    bf8v bfx = *(const bf8v*)&X[(size_t)(tok0+ln)*64 + kof];
    #pragma unroll
    for(int mf=0;mf<8;mf++){
      bf8v af = *(const bf8v*)&W1[(mf*16+ln)*64 + kof];
      a1[mf] = __builtin_amdgcn_mfma_f32_16x16x32_bf16(af, bfx, a1[mf], 0,0,0);
    }
  }
  #pragma unroll
  for(int mf=0;mf<8;mf++){
    float4 bb = *(const float4*)&b1[mf*16+quad*4];
    float h[4] = { fast_tanh(a1[mf][0]+bb.x), fast_tanh(a1[mf][1]+bb.y),
                   fast_tanh(a1[mf][2]+bb.z), fast_tanh(a1[mf][3]+bb.w) };
    *(uint2*)&sH[ln*136 + mf*16+quad*4] = pack4(h);
  }
  float keacc=0.f;
  for(int ch=0; ch<(F>>6); ch++){
    f4v a2[4];
    #pragma unroll
    for(int m=0;m<4;m++) a2[m]=(f4v){0,0,0,0};
    #pragma unroll
    for(int ks=0;ks<4;ks++){
      const int kof = ks*32+quad*8;
      bf8v bfh = *(const bf8v*)&sH[ln*136 + kof];
      #pragma unroll
      for(int mf=0;mf<4;mf++){
        bf8v af = *(const bf8v*)&W2[(size_t)(ch*64+mf*16+ln)*128 + kof];
        a2[mf] = __builtin_amdgcn_mfma_f32_16x16x32_bf16(af, bfh, a2[mf], 0,0,0);
      }
    }
    #pragma unroll
    for(int mf=0;mf<4;mf++){
      float4 bb = *(const float4*)&b2[ch*64 + mf*16+quad*4];
      float d0=a2[mf][0]+bb.x, d1=a2[mf][1]+bb.y, d2=a2[mf][2]+bb.z, d3=a2[mf][3]+bb.w;
      keacc += (d0*d0+d1*d1)+(d2*d2+d3*d3);
      float4 o = {d0,d1,d2,d3};
      *(float4*)&out0[(size_t)(tok0+ln)*512 + ch*64 + mf*16+quad*4] = o;
    }
  }
  float tot = wave_reduce_sum(keacc);
  if(lane==0) slots[blockIdx.x] = 0.5f*tot;
}

// ---------------- ke reduction: 1 block, wave per batch ----------------
__global__ __launch_bounds__(1024) void k_ke(const float* __restrict__ slots, float* __restrict__ keo){
  const int w = threadIdx.x>>6, lane = threadIdx.x&63;
  float s = slots[w*64 + lane];
  s = wave_reduce_sum(s);
  if(lane==0) keo[w] = s;
}

// ---------------- launch ----------------
extern "C" void kernel_launch(void* const* d_in, const int* in_sizes, int n_in,
                              void* d_out, int out_size, void* d_ws, size_t ws_size,
                              hipStream_t stream)
{
  const float* y      = (const float*)d_in[1];
  const float* w1s[4] = {(const float*)d_in[3],(const float*)d_in[4],(const float*)d_in[5],(const float*)d_in[6]};
  const float* w2s[4] = {(const float*)d_in[7],(const float*)d_in[8],(const float*)d_in[9],(const float*)d_in[10]};
  const float* b2s[4] = {(const float*)d_in[11],(const float*)d_in[12],(const float*)d_in[13],(const float*)d_in[14]};
  const float* in_b1  = (const float*)d_in[15];
  const float* in_w2  = (const float*)d_in[16];
  const float* in_b2  = (const float*)d_in[17];
  const float* out_w1 = (const float*)d_in[18];
  const float* out_b1 = (const float*)d_in[19];
  const float* qkv_w  = (const float*)d_in[20];
  const float* qkv_b  = (const float*)d_in[21];
  const float* ao_w   = (const float*)d_in[22];
  const float* ao_b   = (const float*)d_in[23];
  const float* ln1w   = (const float*)d_in[24];
  const float* ln1b   = (const float*)d_in[25];
  const float* fw1    = (const float*)d_in[26];
  const float* fb1    = (const float*)d_in[27];
  const float* fw2    = (const float*)d_in[28];
  const float* fb2    = (const float*)d_in[29];
  const float* ln2w   = (const float*)d_in[30];
  const float* ln2b   = (const float*)d_in[31];

  float* out0 = (float*)d_out;
  float* keo  = out0 + (size_t)16*1024*512;

  ushort* wb  = (ushort*)d_ws;
  ushort* XA  = wb + OFF_XA;
  ushort* XB  = wb + OFF_XB;
  ushort* OB  = wb + OFF_OB;
  ushort* QKB = wb + OFF_QKB;
  ushort* VT  = wb + OFF_VT;
  float* slots = (float*)(wb + OFF_KE);

  k_setup<<<1024,256,0,stream>>>(w1s[0],w1s[1],w1s[2],w1s[3], in_w2, out_w1,
      w2s[0],w2s[1],w2s[2],w2s[3], qkv_w, ao_w, fw1, fw2, wb, out0);

  k_in<<<1024,64,0,stream>>>(y, in_b1, in_b2, qkv_b, wb, XA, QKB, VT);

  k_attn<<<2048,64,0,stream>>>(QKB, VT, OB);
  k_fused<true><<<1024,64,0,stream>>>(XA, OB, wb, 0, ao_b, ln1w, ln1b, fb1, fb2, ln2w, ln2b,
                                      XB, QKB, VT, qkv_b);
  k_attn<<<2048,64,0,stream>>>(QKB, VT, OB);
  k_fused<false><<<1024,64,0,stream>>>(XB, OB, wb, 1, ao_b, ln1w, ln1b, fb1, fb2, ln2w, ln2b,
                                       XA, QKB, VT, qkv_b);

  k_out<<<1024,64,0,stream>>>(XA, wb, out_b1, b2s[0],b2s[1],b2s[2],b2s[3], out0, slots);
  k_ke<<<1,1024,0,stream>>>(slots, keo);
}

// Round 5
// 305.430 us; speedup vs baseline: 2.1181x; 1.0201x over previous
//
#include <hip/hip_runtime.h>
#include <math.h>

typedef short bf8v __attribute__((ext_vector_type(8)));
typedef float f4v  __attribute__((ext_vector_type(4)));

#define QS 0.36067376022224085f  // log2(e)/4

// ---- ws layout (ushort units) ----
#define OFF_IN_W1  0        // per-seg {0,8192,24576,57344}, [128][F]
#define OFF_IN_W2  122880   // + seg*8192, [64][128]
#define OFF_OUT_W1 155648   // + seg*8192, [128][64]
#define OFF_OUT_W2 188416   // per-seg {0,8192,24576,57344}, [F][128]
#define OFF_QKV_W  311296   // + l*12288, [192][64] (Q rows pre-scaled by QS)
#define OFF_AO_W   335872   // + l*4096,  [64][64]
#define OFF_FW1    344064   // + l*16384, [256][64]
#define OFF_FW2    376832   // + l*16384, [64][256]
#define WTOT       409600
#define OFF_XA     409600
#define OFF_XB     1458176
#define OFF_OB     2506752
#define OFF_QKB    3555328  // [tok][128]: Q@0 (prescaled), K@64
#define OFF_VT     5652480  // [b][h][d16][1024] bf16
#define OFF_KE     6701056  // 3840 floats (block partials)
#define OFF_YB     6708736  // y as bf16 [16384][512]

__device__ __forceinline__ ushort bf16_rne(float f){
  uint u = __float_as_uint(f);
  u += 0x7fffu + ((u>>16)&1u);
  return (ushort)(u>>16);
}
__device__ __forceinline__ uint pack2(float a, float b){
  uint ua = __float_as_uint(a); ua += 0x7fffu + ((ua>>16)&1u);
  uint ub = __float_as_uint(b); ub += 0x7fffu + ((ub>>16)&1u);
  return __builtin_amdgcn_perm(ub, ua, 0x07060302u);  // {ub.hi16, ua.hi16}
}
__device__ __forceinline__ float bf2f(uint u){ return __uint_as_float(u<<16); }
__device__ __forceinline__ uint2 pack4(const float v[4]){
  uint2 r; r.x = pack2(v[0],v[1]); r.y = pack2(v[2],v[3]); return r;
}
__device__ __forceinline__ void unpack4(uint2 p, float v[4]){
  v[0]=bf2f(p.x&0xffffu); v[1]=bf2f(p.x>>16); v[2]=bf2f(p.y&0xffffu); v[3]=bf2f(p.y>>16);
}
__device__ __forceinline__ float wave_reduce_sum(float v){
  #pragma unroll
  for(int o=32;o>0;o>>=1) v += __shfl_xor(v, o, 64);
  return v;
}
__device__ __forceinline__ float fast_tanh(float x){
  float t = __builtin_amdgcn_exp2f(2.8853900817779268f*x);   // exp(2x)
  return (t-1.f)*__builtin_amdgcn_rcpf(t+1.f);
}
__device__ __forceinline__ int seg_w1off(int seg){
  return (seg==0)?0:(seg==1)?8192:(seg==2)?24576:57344;
}

// ---------------- setup: weights->bf16, out0 pad zero, y->bf16 ----------------
__global__ __launch_bounds__(256) void k_setup(
    const float* __restrict__ iw10, const float* __restrict__ iw11,
    const float* __restrict__ iw12, const float* __restrict__ iw13,
    const float* __restrict__ iw2,  const float* __restrict__ ow1,
    const float* __restrict__ ow20, const float* __restrict__ ow21,
    const float* __restrict__ ow22, const float* __restrict__ ow23,
    const float* __restrict__ qkvw, const float* __restrict__ aow,
    const float* __restrict__ f1,   const float* __restrict__ f2,
    const float* __restrict__ y,
    ushort* __restrict__ wb, float* __restrict__ out0, ushort* __restrict__ YB)
{
  const int tid = threadIdx.x;
  if(blockIdx.x < 512){
    for(int i = blockIdx.x*256 + tid; i < WTOT; i += 512*256){
      float v; int j = i;
      if(j < 122880){
        if(j<8192) v=iw10[j];
        else if(j<24576) v=iw11[j-8192];
        else if(j<57344) v=iw12[j-24576];
        else v=iw13[j-57344];
      } else if(j < 155648) v = iw2[j-122880];
      else if(j < 188416) v = ow1[j-155648];
      else if(j < 311296){
        j -= 188416;
        if(j<8192) v=ow20[j];
        else if(j<24576) v=ow21[j-8192];
        else if(j<57344) v=ow22[j-24576];
        else v=ow23[j-57344];
      } else if(j < 335872){
        j -= 311296; v = qkvw[j];
        if(((j>>6)%192) < 64) v *= QS;
      } else if(j < 344064) v = aow[j-335872];
      else if(j < 376832) v = f1[j-344064];
      else v = f2[j-376832];
      wb[i] = bf16_rne(v);
    }
  } else if(blockIdx.x < 1024){
    for(int i = (blockIdx.x-512)*256 + tid; i < 16384*112; i += 512*256){
      int t = i/112, c = 64 + (i%112)*4;
      int F = 64 << ((t>>8)&3);
      if(c >= F){ float4 z={0,0,0,0}; *(float4*)&out0[(size_t)t*512 + c] = z; }
    }
  } else {
    for(int i = (blockIdx.x-1024)*256 + tid; i < 2097152; i += 1024*256){
      float4 v = *(const float4*)&y[(size_t)i*4];
      uint2 o; o.x = pack2(v.x,v.y); o.y = pack2(v.z,v.w);
      *(uint2*)&YB[(size_t)i*4] = o;
    }
  }
}

// ---------------- input MLP + QKV(l=0): 1024 blocks x 1 wave x 16 tokens ----------------
__global__ __launch_bounds__(64) void k_in(
    const ushort* __restrict__ YB, const float* __restrict__ b1g, const float* __restrict__ b2g,
    const float* __restrict__ bqg, const ushort* __restrict__ wb,
    ushort* __restrict__ X, ushort* __restrict__ QKB, ushort* __restrict__ VT)
{
  __shared__ ushort sH[16*136];
  __shared__ ushort sX[16*72];
  const int lane=threadIdx.x, ln=lane&15, quad=lane>>4;
  const int tok0=blockIdx.x*16;
  const int seg=(tok0>>8)&3, F=64<<seg, b=tok0>>10;
  const ushort* W1 = wb + OFF_IN_W1 + seg_w1off(seg);
  const ushort* W2 = wb + OFF_IN_W2 + seg*8192;
  const ushort* Wq = wb + OFF_QKV_W;
  const float* b1 = b1g + seg*128;
  const float* b2 = b2g + seg*64;

  f4v a1[8];
  #pragma unroll
  for(int m=0;m<8;m++) a1[m]=(f4v){0,0,0,0};
  const int nk = F>>5;
  for(int ks=0; ks<nk; ks++){
    const int kof = ks*32 + quad*8;
    bf8v bfy = *(const bf8v*)&YB[(size_t)(tok0+ln)*512 + kof];
    #pragma unroll
    for(int mf=0;mf<8;mf++){
      bf8v af = *(const bf8v*)&W1[(size_t)(mf*16+ln)*F + kof];
      a1[mf] = __builtin_amdgcn_mfma_f32_16x16x32_bf16(af, bfy, a1[mf], 0,0,0);
    }
  }
  #pragma unroll
  for(int mf=0;mf<8;mf++){
    float4 bb = *(const float4*)&b1[mf*16+quad*4];
    float h[4] = { fast_tanh(a1[mf][0]+bb.x), fast_tanh(a1[mf][1]+bb.y),
                   fast_tanh(a1[mf][2]+bb.z), fast_tanh(a1[mf][3]+bb.w) };
    *(uint2*)&sH[ln*136 + mf*16+quad*4] = pack4(h);
  }
  f4v a2[4];
  #pragma unroll
  for(int m=0;m<4;m++) a2[m]=(f4v){0,0,0,0};
  #pragma unroll
  for(int ks=0;ks<4;ks++){
    const int kof = ks*32+quad*8;
    bf8v bfh = *(const bf8v*)&sH[ln*136 + kof];
    #pragma unroll
    for(int mf=0;mf<4;mf++){
      bf8v af = *(const bf8v*)&W2[(mf*16+ln)*128 + kof];
      a2[mf] = __builtin_amdgcn_mfma_f32_16x16x32_bf16(af, bfh, a2[mf], 0,0,0);
    }
  }
  #pragma unroll
  for(int mf=0;mf<4;mf++){
    float4 bb = *(const float4*)&b2[mf*16+quad*4];
    float o[4] = { a2[mf][0]+bb.x, a2[mf][1]+bb.y, a2[mf][2]+bb.z, a2[mf][3]+bb.w };
    uint2 u = pack4(o);
    *(uint2*)&X[(size_t)(tok0+ln)*64 + mf*16+quad*4] = u;
    *(uint2*)&sX[ln*72 + mf*16+quad*4] = u;
  }
  // QKV tail (layer 0)
  f4v aq[12];
  #pragma unroll
  for(int m=0;m<12;m++) aq[m]=(f4v){0,0,0,0};
  #pragma unroll
  for(int ks=0;ks<2;ks++){
    const int kof = ks*32+quad*8;
    bf8v bfx = *(const bf8v*)&sX[ln*72 + kof];
    #pragma unroll
    for(int mf=0;mf<12;mf++){
      bf8v af = *(const bf8v*)&Wq[(mf*16+ln)*64 + kof];
      aq[mf] = __builtin_amdgcn_mfma_f32_16x16x32_bf16(af, bfx, aq[mf], 0,0,0);
    }
  }
  #pragma unroll
  for(int mf=0;mf<8;mf++){
    const int f0 = mf*16+quad*4;
    float4 bb = *(const float4*)&bqg[f0];
    const float s = (mf<4)?QS:1.f;
    float o[4] = { aq[mf][0]+bb.x*s, aq[mf][1]+bb.y*s, aq[mf][2]+bb.z*s, aq[mf][3]+bb.w*s };
    *(uint2*)&QKB[(size_t)(tok0+ln)*128 + f0] = pack4(o);
  }
  #pragma unroll
  for(int mf=8;mf<12;mf++){
    const int h = mf-8;
    float4 bb = *(const float4*)&bqg[128 + h*16 + quad*4];
    float bv[4]={bb.x,bb.y,bb.z,bb.w};
    #pragma unroll
    for(int r=0;r<4;r++)
      VT[(size_t)((b*4+h)*16 + quad*4+r)*1024 + tok0+ln] = bf16_rne(aq[mf][r]+bv[r]);
  }
}

// ---------------- attention: 4096 blocks x 1 wave x 16 q ----------------
__global__ __launch_bounds__(64) void k_attn(
    const ushort* __restrict__ QKB, const ushort* __restrict__ VT, ushort* __restrict__ O)
{
  __shared__ ushort sP[16*72];
  const int lane=threadIdx.x, ln=lane&15, quad=lane>>4;
  const int qb=blockIdx.x&63, h=(blockIdx.x>>6)&3, b=blockIdx.x>>8;
  const int rowQ0 = b*1024 + qb*16;
  const int rowK0 = b*1024;
  const ushort* VTh = VT + (size_t)((b*4+h)*16)*1024;

  const bf8v zf = {0,0,0,0,0,0,0,0};
  bf8v qf = zf;
  if(quad<2) qf = *(const bf8v*)&QKB[(size_t)(rowQ0+ln)*128 + h*16 + quad*8];
  f4v oacc = (f4v){0,0,0,0};
  float lfull = 0.f;

  for(int kc=0;kc<16;kc++){
    #pragma unroll
    for(int ks=0;ks<4;ks++){
      bf8v kf = zf;
      if(quad<2) kf = *(const bf8v*)&QKB[(size_t)(rowK0+kc*64+ks*16+ln)*128 + 64 + h*16 + quad*8];
      f4v st = __builtin_amdgcn_mfma_f32_16x16x32_bf16(kf, qf, (f4v){0,0,0,0}, 0,0,0);
      float p0 = __builtin_amdgcn_exp2f(st[0]);
      float p1 = __builtin_amdgcn_exp2f(st[1]);
      float p2 = __builtin_amdgcn_exp2f(st[2]);
      float p3 = __builtin_amdgcn_exp2f(st[3]);
      lfull += (p0+p1)+(p2+p3);
      uint2 pk; pk.x = pack2(p0,p1); pk.y = pack2(p2,p3);
      *(uint2*)&sP[ln*72 + ks*16+quad*4] = pk;
    }
    #pragma unroll
    for(int kh=0;kh<2;kh++){
      bf8v vf = *(const bf8v*)&VTh[(size_t)ln*1024 + kc*64 + kh*32 + quad*8];
      bf8v pa = *(const bf8v*)&sP[ln*72 + kh*32 + quad*8];
      oacc = __builtin_amdgcn_mfma_f32_16x16x32_bf16(pa, vf, oacc, 0,0,0);
    }
  }
  float l = lfull;
  l += __shfl_xor(l, 16, 64);
  l += __shfl_xor(l, 32, 64);
  #pragma unroll
  for(int r=0;r<4;r++){
    float lr = __shfl(l, quad*4+r, 64);
    float ov = oacc[r]*__builtin_amdgcn_rcpf(lr);
    O[(size_t)(rowQ0+quad*4+r)*64 + h*16 + ln] = bf16_rne(ov);
  }
}

// ---------------- fused proj+LN1+FFN1+FFN2+LN2(+QKV): 1024 blocks x 2 waves x 16 tok ----------------
template<bool DOQ>
__global__ __launch_bounds__(128) void k_fused(
    const ushort* __restrict__ Xin, const ushort* __restrict__ Ob,
    const ushort* __restrict__ wb, int l,
    const float* __restrict__ aob, const float* __restrict__ l1wg, const float* __restrict__ l1bg,
    const float* __restrict__ fb1g, const float* __restrict__ fb2g,
    const float* __restrict__ l2wg, const float* __restrict__ l2bg,
    ushort* __restrict__ Xout, ushort* __restrict__ QKB, ushort* __restrict__ VT,
    const float* __restrict__ bqn)
{
  __shared__ ushort sX[16*72];
  __shared__ ushort sH[16*264];
  __shared__ float2 sStat[2][16];
  const int tid=threadIdx.x, lane=tid&63, w=tid>>6, ln=lane&15, quad=lane>>4;
  const int tok0=blockIdx.x*16, b=tok0>>10;
  const ushort* AO = wb + OFF_AO_W + l*4096;
  const ushort* W1 = wb + OFF_FW1  + l*16384;
  const ushort* W2 = wb + OFF_FW2  + l*16384;

  // proj (duplicated in both waves): A=AO [64][64]
  f4v pa[4];
  #pragma unroll
  for(int m=0;m<4;m++) pa[m]=(f4v){0,0,0,0};
  #pragma unroll
  for(int ks=0;ks<2;ks++){
    const int kof = ks*32+quad*8;
    bf8v bfo = *(const bf8v*)&Ob[(size_t)(tok0+ln)*64 + kof];
    #pragma unroll
    for(int mf=0;mf<4;mf++){
      bf8v af = *(const bf8v*)&AO[(mf*16+ln)*64 + kof];
      pa[mf] = __builtin_amdgcn_mfma_f32_16x16x32_bf16(af, bfo, pa[mf], 0,0,0);
    }
  }
  float v1[4][4]; float s1=0.f, s2=0.f;
  #pragma unroll
  for(int mf=0;mf<4;mf++){
    float4 ab = *(const float4*)&aob[l*64 + mf*16+quad*4];
    float av[4]={ab.x,ab.y,ab.z,ab.w};
    uint2 rx = *(const uint2*)&Xin[(size_t)(tok0+ln)*64 + mf*16+quad*4];
    float rr[4]; unpack4(rx, rr);
    #pragma unroll
    for(int r=0;r<4;r++){ float t=pa[mf][r]+av[r]+rr[r]; v1[mf][r]=t; s1+=t; s2+=t*t; }
  }
  s1 += __shfl_xor(s1,16,64); s1 += __shfl_xor(s1,32,64);
  s2 += __shfl_xor(s2,16,64); s2 += __shfl_xor(s2,32,64);
  float mean = s1*0.015625f, var = s2*0.015625f - mean*mean, rstd = rsqrtf(var+1e-5f);
  float x1[4][4];
  #pragma unroll
  for(int mf=0;mf<4;mf++){
    float4 lw = *(const float4*)&l1wg[l*64 + mf*16+quad*4];
    float4 lb = *(const float4*)&l1bg[l*64 + mf*16+quad*4];
    float wv[4]={lw.x,lw.y,lw.z,lw.w}, bv[4]={lb.x,lb.y,lb.z,lb.w};
    #pragma unroll
    for(int r=0;r<4;r++) x1[mf][r]=(v1[mf][r]-mean)*rstd*wv[r]+bv[r];
    *(uint2*)&sX[ln*72 + mf*16+quad*4] = pack4(x1[mf]);   // both waves write identical data
  }
  // FFN1: wave w computes hidden [128w,128w+128): 8 m-frags (same-wave sX RAW, no barrier)
  f4v f1[8];
  #pragma unroll
  for(int m=0;m<8;m++) f1[m]=(f4v){0,0,0,0};
  #pragma unroll
  for(int ks=0;ks<2;ks++){
    const int kof = ks*32+quad*8;
    bf8v bfx = *(const bf8v*)&sX[ln*72 + kof];
    #pragma unroll
    for(int mf=0;mf<8;mf++){
      bf8v af = *(const bf8v*)&W1[((w*8+mf)*16+ln)*64 + kof];
      f1[mf] = __builtin_amdgcn_mfma_f32_16x16x32_bf16(af, bfx, f1[mf], 0,0,0);
    }
  }
  #pragma unroll
  for(int mf=0;mf<8;mf++){
    const int f0 = (w*8+mf)*16+quad*4;
    float4 bb = *(const float4*)&fb1g[l*256 + f0];
    float h[4] = { fmaxf(f1[mf][0]+bb.x,0.f), fmaxf(f1[mf][1]+bb.y,0.f),
                   fmaxf(f1[mf][2]+bb.z,0.f), fmaxf(f1[mf][3]+bb.w,0.f) };
    *(uint2*)&sH[ln*264 + f0] = pack4(h);
  }
  __syncthreads();
  // FFN2: wave w computes features [32w,32w+32): 2 m-frags over full K=256
  f4v f2[2] = {(f4v){0,0,0,0},(f4v){0,0,0,0}};
  #pragma unroll
  for(int ks=0;ks<8;ks++){
    const int kof = ks*32+quad*8;
    bf8v bfh = *(const bf8v*)&sH[ln*264 + kof];
    #pragma unroll
    for(int mf=0;mf<2;mf++){
      bf8v af = *(const bf8v*)&W2[((w*2+mf)*16+ln)*256 + kof];
      f2[mf] = __builtin_amdgcn_mfma_f32_16x16x32_bf16(af, bfh, f2[mf], 0,0,0);
    }
  }
  float v2[2][4]; s1=0.f; s2=0.f;
  #pragma unroll
  for(int mf=0;mf<2;mf++){
    const int gmf = w*2+mf;
    float4 bb = *(const float4*)&fb2g[l*64 + gmf*16+quad*4];
    float bv[4]={bb.x,bb.y,bb.z,bb.w};
    #pragma unroll
    for(int r=0;r<4;r++){ float t=f2[mf][r]+bv[r]+x1[gmf][r]; v2[mf][r]=t; s1+=t; s2+=t*t; }
  }
  s1 += __shfl_xor(s1,16,64); s1 += __shfl_xor(s1,32,64);
  s2 += __shfl_xor(s2,16,64); s2 += __shfl_xor(s2,32,64);
  if(quad==0) sStat[w][ln] = make_float2(s1,s2);
  __syncthreads();
  {
    float2 sa = sStat[0][ln], sb = sStat[1][ln];
    float t1 = sa.x+sb.x, t2 = sa.y+sb.y;
    mean = t1*0.015625f; var = t2*0.015625f - mean*mean; rstd = rsqrtf(var+1e-5f);
  }
  #pragma unroll
  for(int mf=0;mf<2;mf++){
    const int gmf = w*2+mf;
    float4 lw = *(const float4*)&l2wg[l*64 + gmf*16+quad*4];
    float4 lb = *(const float4*)&l2bg[l*64 + gmf*16+quad*4];
    float wv[4]={lw.x,lw.y,lw.z,lw.w}, bv[4]={lb.x,lb.y,lb.z,lb.w};
    float xo[4];
    #pragma unroll
    for(int r=0;r<4;r++) xo[r]=(v2[mf][r]-mean)*rstd*wv[r]+bv[r];
    uint2 u = pack4(xo);
    *(uint2*)&Xout[(size_t)(tok0+ln)*64 + gmf*16+quad*4] = u;
    *(uint2*)&sX[ln*72 + gmf*16+quad*4] = u;
  }
  if(DOQ){
    __syncthreads();
    const ushort* Wq = wb + OFF_QKV_W + (l+1)*12288;
    const float* bq = bqn + (l+1)*192;
    f4v aq[6];
    #pragma unroll
    for(int m=0;m<6;m++) aq[m]=(f4v){0,0,0,0};
    #pragma unroll
    for(int ks=0;ks<2;ks++){
      const int kof = ks*32+quad*8;
      bf8v bfx = *(const bf8v*)&sX[ln*72 + kof];
      #pragma unroll
      for(int i=0;i<6;i++){
        bf8v af = *(const bf8v*)&Wq[((w*6+i)*16+ln)*64 + kof];
        aq[i] = __builtin_amdgcn_mfma_f32_16x16x32_bf16(af, bfx, aq[i], 0,0,0);
      }
    }
    #pragma unroll
    for(int i=0;i<6;i++){
      const int gmf = w*6+i;
      if(gmf<8){
        const int f0 = gmf*16+quad*4;
        float4 bb = *(const float4*)&bq[f0];
        const float s = (gmf<4)?QS:1.f;
        float o[4] = { aq[i][0]+bb.x*s, aq[i][1]+bb.y*s, aq[i][2]+bb.z*s, aq[i][3]+bb.w*s };
        *(uint2*)&QKB[(size_t)(tok0+ln)*128 + f0] = pack4(o);
      } else {
        const int h = gmf-8;
        float4 bb = *(const float4*)&bq[128 + h*16 + quad*4];
        float bv[4]={bb.x,bb.y,bb.z,bb.w};
        #pragma unroll
        for(int r=0;r<4;r++)
          VT[(size_t)((b*4+h)*16 + quad*4+r)*1024 + tok0+ln] = bf16_rne(aq[i][r]+bv[r]);
      }
    }
  }
}

// ---------------- output head: 3840 blocks x 1 wave (token-group x chunk) ----------------
__global__ __launch_bounds__(64) void k_out(
    const ushort* __restrict__ X, const ushort* __restrict__ wb,
    const float* __restrict__ ob1g,
    const float* __restrict__ b20, const float* __restrict__ b21,
    const float* __restrict__ b22, const float* __restrict__ b23,
    float* __restrict__ out0, float* __restrict__ slots)
{
  __shared__ ushort sH[16*136];
  const int lane=threadIdx.x, ln=lane&15, quad=lane>>4;
  const int bid=blockIdx.x;
  const int b = bid/240;
  int r = bid - b*240;
  int seg, tg, ch;
  if(r<16){ seg=0; tg=r; ch=0; }
  else if(r<48){ seg=1; r-=16; tg=r>>1; ch=r&1; }
  else if(r<112){ seg=2; r-=48; tg=r>>2; ch=r&3; }
  else { seg=3; r-=112; tg=r>>3; ch=r&7; }
  const int tok0 = b*1024 + seg*256 + tg*16;
  const ushort* W1 = wb + OFF_OUT_W1 + seg*8192;
  const ushort* W2 = wb + OFF_OUT_W2 + seg_w1off(seg) + (size_t)(ch*64)*128;
  const float* b1 = ob1g + seg*128;
  const float* b2 = (seg==0?b20: seg==1?b21: seg==2?b22: b23) + ch*64;

  f4v a1[8];
  #pragma unroll
  for(int m=0;m<8;m++) a1[m]=(f4v){0,0,0,0};
  #pragma unroll
  for(int ks=0;ks<2;ks++){
    const int kof = ks*32+quad*8;
    bf8v bfx = *(const bf8v*)&X[(size_t)(tok0+ln)*64 + kof];
    #pragma unroll
    for(int mf=0;mf<8;mf++){
      bf8v af = *(const bf8v*)&W1[(mf*16+ln)*64 + kof];
      a1[mf] = __builtin_amdgcn_mfma_f32_16x16x32_bf16(af, bfx, a1[mf], 0,0,0);
    }
  }
  #pragma unroll
  for(int mf=0;mf<8;mf++){
    float4 bb = *(const float4*)&b1[mf*16+quad*4];
    float h[4] = { fast_tanh(a1[mf][0]+bb.x), fast_tanh(a1[mf][1]+bb.y),
                   fast_tanh(a1[mf][2]+bb.z), fast_tanh(a1[mf][3]+bb.w) };
    *(uint2*)&sH[ln*136 + mf*16+quad*4] = pack4(h);
  }
  f4v a2[4];
  #pragma unroll
  for(int m=0;m<4;m++) a2[m]=(f4v){0,0,0,0};
  #pragma unroll
  for(int ks=0;ks<4;ks++){
    const int kof = ks*32+quad*8;
    bf8v bfh = *(const bf8v*)&sH[ln*136 + kof];
    #pragma unroll
    for(int mf=0;mf<4;mf++){
      bf8v af = *(const bf8v*)&W2[(size_t)(mf*16+ln)*128 + kof];
      a2[mf] = __builtin_amdgcn_mfma_f32_16x16x32_bf16(af, bfh, a2[mf], 0,0,0);
    }
  }
  float keacc=0.f;
  #pragma unroll
  for(int mf=0;mf<4;mf++){
    float4 bb = *(const float4*)&b2[mf*16+quad*4];
    float d0=a2[mf][0]+bb.x, d1=a2[mf][1]+bb.y, d2=a2[mf][2]+bb.z, d3=a2[mf][3]+bb.w;
    keacc += (d0*d0+d1*d1)+(d2*d2+d3*d3);
    float4 o = {d0,d1,d2,d3};
    *(float4*)&out0[(size_t)(tok0+ln)*512 + ch*64 + mf*16+quad*4] = o;
  }
  float tot = wave_reduce_sum(keacc);
  if(lane==0) slots[bid] = 0.5f*tot;
}

// ---------------- ke reduction ----------------
__global__ __launch_bounds__(1024) void k_ke(const float* __restrict__ slots, float* __restrict__ keo){
  const int w = threadIdx.x>>6, lane = threadIdx.x&63;
  float s = 0.f;
  for(int i=lane;i<240;i+=64) s += slots[w*240 + i];
  s = wave_reduce_sum(s);
  if(lane==0) keo[w] = s;
}

// ---------------- launch ----------------
extern "C" void kernel_launch(void* const* d_in, const int* in_sizes, int n_in,
                              void* d_out, int out_size, void* d_ws, size_t ws_size,
                              hipStream_t stream)
{
  const float* y      = (const float*)d_in[1];
  const float* w1s[4] = {(const float*)d_in[3],(const float*)d_in[4],(const float*)d_in[5],(const float*)d_in[6]};
  const float* w2s[4] = {(const float*)d_in[7],(const float*)d_in[8],(const float*)d_in[9],(const float*)d_in[10]};
  const float* b2s[4] = {(const float*)d_in[11],(const float*)d_in[12],(const float*)d_in[13],(const float*)d_in[14]};
  const float* in_b1  = (const float*)d_in[15];
  const float* in_w2  = (const float*)d_in[16];
  const float* in_b2  = (const float*)d_in[17];
  const float* out_w1 = (const float*)d_in[18];
  const float* out_b1 = (const float*)d_in[19];
  const float* qkv_w  = (const float*)d_in[20];
  const float* qkv_b  = (const float*)d_in[21];
  const float* ao_w   = (const float*)d_in[22];
  const float* ao_b   = (const float*)d_in[23];
  const float* ln1w   = (const float*)d_in[24];
  const float* ln1b   = (const float*)d_in[25];
  const float* fw1    = (const float*)d_in[26];
  const float* fb1    = (const float*)d_in[27];
  const float* fw2    = (const float*)d_in[28];
  const float* fb2    = (const float*)d_in[29];
  const float* ln2w   = (const float*)d_in[30];
  const float* ln2b   = (const float*)d_in[31];

  float* out0 = (float*)d_out;
  float* keo  = out0 + (size_t)16*1024*512;

  ushort* wb  = (ushort*)d_ws;
  ushort* XA  = wb + OFF_XA;
  ushort* XB  = wb + OFF_XB;
  ushort* OB  = wb + OFF_OB;
  ushort* QKB = wb + OFF_QKB;
  ushort* VT  = wb + OFF_VT;
  float* slots = (float*)(wb + OFF_KE);
  ushort* YB  = wb + OFF_YB;

  k_setup<<<2048,256,0,stream>>>(w1s[0],w1s[1],w1s[2],w1s[3], in_w2, out_w1,
      w2s[0],w2s[1],w2s[2],w2s[3], qkv_w, ao_w, fw1, fw2, y, wb, out0, YB);

  k_in<<<1024,64,0,stream>>>(YB, in_b1, in_b2, qkv_b, wb, XA, QKB, VT);

  k_attn<<<4096,64,0,stream>>>(QKB, VT, OB);
  k_fused<true><<<1024,128,0,stream>>>(XA, OB, wb, 0, ao_b, ln1w, ln1b, fb1, fb2, ln2w, ln2b,
                                       XB, QKB, VT, qkv_b);
  k_attn<<<4096,64,0,stream>>>(QKB, VT, OB);
  k_fused<false><<<1024,128,0,stream>>>(XB, OB, wb, 1, ao_b, ln1w, ln1b, fb1, fb2, ln2w, ln2b,
                                        XA, QKB, VT, qkv_b);

  k_out<<<3840,64,0,stream>>>(XA, wb, out_b1, b2s[0],b2s[1],b2s[2],b2s[3], out0, slots);
  k_ke<<<1,1024,0,stream>>>(slots, keo);
}

// Round 6
// 288.110 us; speedup vs baseline: 2.2454x; 1.0601x over previous
//
#include <hip/hip_runtime.h>
#include <math.h>

typedef short bf8v __attribute__((ext_vector_type(8)));
typedef float f4v  __attribute__((ext_vector_type(4)));

#define QS 0.36067376022224085f  // log2(e)/4

// ---- ws layout (ushort units) ----
#define OFF_IN_W1  0        // per-seg {0,8192,24576,57344}, [128][F]
#define OFF_IN_W2  122880   // + seg*8192, [64][128]
#define OFF_OUT_W1 155648   // + seg*8192, [128][64]
#define OFF_OUT_W2 188416   // per-seg {0,8192,24576,57344}, [F][128]
#define OFF_QKV_W  311296   // + l*12288, [192][64] (Q rows pre-scaled by QS)
#define OFF_AO_W   335872   // + l*4096,  [64][64]
#define OFF_FW1    344064   // + l*16384, [256][64]
#define OFF_FW2    376832   // + l*16384, [64][256]
#define WTOT       409600
#define OFF_XA     409600
#define OFF_XB     1458176
#define OFF_QC0    2506752  // [b][h][1024][16] bf16 (Q prescaled)
#define OFF_KC0    3555328  // [b][h][1024][16]
#define OFF_VT0    4603904  // [b][h][16][1024]
#define OFF_QC1    5652480
#define OFF_KC1    6701056
#define OFF_VT1    7749632
#define OFF_KE     8798208  // 3840 floats

__device__ __forceinline__ ushort bf16_rne(float f){
  uint u = __float_as_uint(f);
  u += 0x7fffu + ((u>>16)&1u);
  return (ushort)(u>>16);
}
__device__ __forceinline__ uint pack2(float a, float b){
  uint ua = __float_as_uint(a); ua += 0x7fffu + ((ua>>16)&1u);
  uint ub = __float_as_uint(b); ub += 0x7fffu + ((ub>>16)&1u);
  return __builtin_amdgcn_perm(ub, ua, 0x07060302u);
}
__device__ __forceinline__ float bf2f(uint u){ return __uint_as_float(u<<16); }
__device__ __forceinline__ uint2 pack4(const float v[4]){
  uint2 r; r.x = pack2(v[0],v[1]); r.y = pack2(v[2],v[3]); return r;
}
__device__ __forceinline__ void unpack4(uint2 p, float v[4]){
  v[0]=bf2f(p.x&0xffffu); v[1]=bf2f(p.x>>16); v[2]=bf2f(p.y&0xffffu); v[3]=bf2f(p.y>>16);
}
__device__ __forceinline__ float wave_reduce_sum(float v){
  #pragma unroll
  for(int o=32;o>0;o>>=1) v += __shfl_xor(v, o, 64);
  return v;
}
__device__ __forceinline__ float fast_tanh(float x){
  float t = __builtin_amdgcn_exp2f(2.8853900817779268f*x);
  return (t-1.f)*__builtin_amdgcn_rcpf(t+1.f);
}
__device__ __forceinline__ int seg_w1off(int seg){
  return (seg==0)?0:(seg==1)?8192:(seg==2)?24576:57344;
}

// ---------------- setup: weights->bf16 + out0 pad zero ----------------
__global__ __launch_bounds__(256) void k_setup(
    const float* __restrict__ iw10, const float* __restrict__ iw11,
    const float* __restrict__ iw12, const float* __restrict__ iw13,
    const float* __restrict__ iw2,  const float* __restrict__ ow1,
    const float* __restrict__ ow20, const float* __restrict__ ow21,
    const float* __restrict__ ow22, const float* __restrict__ ow23,
    const float* __restrict__ qkvw, const float* __restrict__ aow,
    const float* __restrict__ f1,   const float* __restrict__ f2,
    ushort* __restrict__ wb, float* __restrict__ out0)
{
  const int tid = threadIdx.x;
  if(blockIdx.x < 512){
    for(int i = blockIdx.x*256 + tid; i < WTOT; i += 512*256){
      float v; int j = i;
      if(j < 122880){
        if(j<8192) v=iw10[j];
        else if(j<24576) v=iw11[j-8192];
        else if(j<57344) v=iw12[j-24576];
        else v=iw13[j-57344];
      } else if(j < 155648) v = iw2[j-122880];
      else if(j < 188416) v = ow1[j-155648];
      else if(j < 311296){
        j -= 188416;
        if(j<8192) v=ow20[j];
        else if(j<24576) v=ow21[j-8192];
        else if(j<57344) v=ow22[j-24576];
        else v=ow23[j-57344];
      } else if(j < 335872){
        j -= 311296; v = qkvw[j];
        if(((j>>6)%192) < 64) v *= QS;
      } else if(j < 344064) v = aow[j-335872];
      else if(j < 376832) v = f1[j-344064];
      else v = f2[j-376832];
      wb[i] = bf16_rne(v);
    }
  } else {
    for(int i = (blockIdx.x-512)*256 + tid; i < 16384*112; i += 512*256){
      int t = i/112, c = 64 + (i%112)*4;
      int F = 64 << ((t>>8)&3);
      if(c >= F){ float4 z={0,0,0,0}; *(float4*)&out0[(size_t)t*512 + c] = z; }
    }
  }
}

// ---------------- input MLP + QKV(l=0): 1024 blocks x 1 wave x 16 tokens ----------------
__global__ __launch_bounds__(64) void k_in(
    const float* __restrict__ y, const float* __restrict__ b1g, const float* __restrict__ b2g,
    const float* __restrict__ bqg, const ushort* __restrict__ wb,
    ushort* __restrict__ X, ushort* __restrict__ QC, ushort* __restrict__ KC,
    ushort* __restrict__ VT)
{
  __shared__ ushort sH[16*136];
  __shared__ ushort sX[16*72];
  const int lane=threadIdx.x, ln=lane&15, quad=lane>>4;
  const int tok0=blockIdx.x*16;
  const int seg=(tok0>>8)&3, F=64<<seg, b=tok0>>10;
  const ushort* W1 = wb + OFF_IN_W1 + seg_w1off(seg);
  const ushort* W2 = wb + OFF_IN_W2 + seg*8192;
  const ushort* Wq = wb + OFF_QKV_W;
  const float* b1 = b1g + seg*128;
  const float* b2 = b2g + seg*64;

  f4v a1[8];
  #pragma unroll
  for(int m=0;m<8;m++) a1[m]=(f4v){0,0,0,0};
  const int nk = F>>5;
  for(int ks=0; ks<nk; ks++){
    const int kof = ks*32 + quad*8;
    const float* yp = &y[(size_t)(tok0+ln)*512 + kof];
    float4 a = *(const float4*)yp;
    float4 c = *(const float4*)(yp+4);
    union{bf8v v; uint us[4];} u;
    u.us[0]=pack2(a.x,a.y); u.us[1]=pack2(a.z,a.w);
    u.us[2]=pack2(c.x,c.y); u.us[3]=pack2(c.z,c.w);
    #pragma unroll
    for(int mf=0;mf<8;mf++){
      bf8v af = *(const bf8v*)&W1[(size_t)(mf*16+ln)*F + kof];
      a1[mf] = __builtin_amdgcn_mfma_f32_16x16x32_bf16(af, u.v, a1[mf], 0,0,0);
    }
  }
  #pragma unroll
  for(int mf=0;mf<8;mf++){
    float4 bb = *(const float4*)&b1[mf*16+quad*4];
    float h[4] = { fast_tanh(a1[mf][0]+bb.x), fast_tanh(a1[mf][1]+bb.y),
                   fast_tanh(a1[mf][2]+bb.z), fast_tanh(a1[mf][3]+bb.w) };
    *(uint2*)&sH[ln*136 + mf*16+quad*4] = pack4(h);
  }
  f4v a2[4];
  #pragma unroll
  for(int m=0;m<4;m++) a2[m]=(f4v){0,0,0,0};
  #pragma unroll
  for(int ks=0;ks<4;ks++){
    const int kof = ks*32+quad*8;
    bf8v bfh = *(const bf8v*)&sH[ln*136 + kof];
    #pragma unroll
    for(int mf=0;mf<4;mf++){
      bf8v af = *(const bf8v*)&W2[(mf*16+ln)*128 + kof];
      a2[mf] = __builtin_amdgcn_mfma_f32_16x16x32_bf16(af, bfh, a2[mf], 0,0,0);
    }
  }
  #pragma unroll
  for(int mf=0;mf<4;mf++){
    float4 bb = *(const float4*)&b2[mf*16+quad*4];
    float o[4] = { a2[mf][0]+bb.x, a2[mf][1]+bb.y, a2[mf][2]+bb.z, a2[mf][3]+bb.w };
    uint2 u = pack4(o);
    *(uint2*)&X[(size_t)(tok0+ln)*64 + mf*16+quad*4] = u;
    *(uint2*)&sX[ln*72 + mf*16+quad*4] = u;
  }
  // QKV tail (layer 0)
  f4v aq[12];
  #pragma unroll
  for(int m=0;m<12;m++) aq[m]=(f4v){0,0,0,0};
  #pragma unroll
  for(int ks=0;ks<2;ks++){
    const int kof = ks*32+quad*8;
    bf8v bfx = *(const bf8v*)&sX[ln*72 + kof];
    #pragma unroll
    for(int mf=0;mf<12;mf++){
      bf8v af = *(const bf8v*)&Wq[(mf*16+ln)*64 + kof];
      aq[mf] = __builtin_amdgcn_mfma_f32_16x16x32_bf16(af, bfx, aq[mf], 0,0,0);
    }
  }
  #pragma unroll
  for(int mf=0;mf<4;mf++){   // Q (prescaled weights; scale bias too)
    float4 bb = *(const float4*)&bqg[mf*16+quad*4];
    float o[4] = { aq[mf][0]+bb.x*QS, aq[mf][1]+bb.y*QS, aq[mf][2]+bb.z*QS, aq[mf][3]+bb.w*QS };
    *(uint2*)&QC[((size_t)(b*4+mf)*1024 + tok0+ln)*16 + quad*4] = pack4(o);
  }
  #pragma unroll
  for(int mf=4;mf<8;mf++){   // K
    float4 bb = *(const float4*)&bqg[mf*16+quad*4];
    float o[4] = { aq[mf][0]+bb.x, aq[mf][1]+bb.y, aq[mf][2]+bb.z, aq[mf][3]+bb.w };
    *(uint2*)&KC[((size_t)(b*4+mf-4)*1024 + tok0+ln)*16 + quad*4] = pack4(o);
  }
  #pragma unroll
  for(int mf=8;mf<12;mf++){  // V transposed
    const int h = mf-8;
    float4 bb = *(const float4*)&bqg[128 + h*16 + quad*4];
    float bv[4]={bb.x,bb.y,bb.z,bb.w};
    #pragma unroll
    for(int r=0;r<4;r++)
      VT[(size_t)((b*4+h)*16 + quad*4+r)*1024 + tok0+ln] = bf16_rne(aq[mf][r]+bv[r]);
  }
}

// ---------------- fused attn+proj+LN1+FFN1+FFN2+LN2(+QKV next) ----------------
// 1024 blocks x 4 waves x 16 tokens; wave = head during attention.
template<bool DOQ>
__global__ __launch_bounds__(256) void k_af(
    const ushort* __restrict__ Xin, const ushort* __restrict__ wb, int l,
    const float* __restrict__ aob, const float* __restrict__ l1wg, const float* __restrict__ l1bg,
    const float* __restrict__ fb1g, const float* __restrict__ fb2g,
    const float* __restrict__ l2wg, const float* __restrict__ l2bg,
    ushort* __restrict__ Xout,
    const ushort* __restrict__ QC, const ushort* __restrict__ KC, const ushort* __restrict__ VT,
    ushort* __restrict__ QCn, ushort* __restrict__ KCn, ushort* __restrict__ VTn,
    const float* __restrict__ bqn)
{
  __shared__ ushort sP[4][16*72];
  __shared__ ushort sO[16*72];
  __shared__ ushort sX[16*72];
  __shared__ ushort sHH[16*264];
  __shared__ float2 sStat[4][16];
  const int tid=threadIdx.x, lane=tid&63, w=tid>>6, ln=lane&15, quad=lane>>4;
  const int tok0=blockIdx.x*16, b=tok0>>10;
  const ushort* QCh = QC + (size_t)(b*4+w)*1024*16;
  const ushort* KCh = KC + (size_t)(b*4+w)*1024*16;
  const ushort* VTh = VT + (size_t)(b*4+w)*16*1024;

  // ---- attention (wave w = head w, 16 q rows) ----
  const bf8v zf={0,0,0,0,0,0,0,0};
  bf8v qf=zf;
  if(quad<2) qf = *(const bf8v*)&QCh[(size_t)(tok0+ln)*16 + quad*8];
  f4v oacc=(f4v){0,0,0,0};
  float lfull=0.f;
  ushort* Pw = sP[w];
  for(int kc=0;kc<16;kc++){
    #pragma unroll
    for(int ks=0;ks<4;ks++){
      bf8v kf=zf;
      if(quad<2) kf = *(const bf8v*)&KCh[(size_t)(kc*64+ks*16+ln)*16 + quad*8];
      f4v st = __builtin_amdgcn_mfma_f32_16x16x32_bf16(kf, qf, (f4v){0,0,0,0}, 0,0,0);
      float p0=__builtin_amdgcn_exp2f(st[0]);
      float p1=__builtin_amdgcn_exp2f(st[1]);
      float p2=__builtin_amdgcn_exp2f(st[2]);
      float p3=__builtin_amdgcn_exp2f(st[3]);
      lfull += (p0+p1)+(p2+p3);
      uint2 pk; pk.x=pack2(p0,p1); pk.y=pack2(p2,p3);
      *(uint2*)&Pw[ln*72 + ks*16+quad*4] = pk;
    }
    #pragma unroll
    for(int kh=0;kh<2;kh++){
      bf8v vf = *(const bf8v*)&VTh[(size_t)ln*1024 + kc*64 + kh*32 + quad*8];
      bf8v pa = *(const bf8v*)&Pw[ln*72 + kh*32 + quad*8];
      oacc = __builtin_amdgcn_mfma_f32_16x16x32_bf16(pa, vf, oacc, 0,0,0);
    }
  }
  {
    float lq = lfull;
    lq += __shfl_xor(lq, 16, 64);
    lq += __shfl_xor(lq, 32, 64);
    #pragma unroll
    for(int r=0;r<4;r++){
      float lr = __shfl(lq, quad*4+r, 64);
      float ov = oacc[r]*__builtin_amdgcn_rcpf(lr);
      sO[(quad*4+r)*72 + w*16 + ln] = bf16_rne(ov);   // O[q][h*16+d]
    }
  }
  __syncthreads();

  // ---- proj + residual + LN1 (full 64 features per wave, duplicated) ----
  const ushort* AO = wb + OFF_AO_W + l*4096;
  f4v pr[4];
  #pragma unroll
  for(int m=0;m<4;m++) pr[m]=(f4v){0,0,0,0};
  #pragma unroll
  for(int ks=0;ks<2;ks++){
    const int kof = ks*32+quad*8;
    bf8v bfo = *(const bf8v*)&sO[ln*72 + kof];
    #pragma unroll
    for(int mf=0;mf<4;mf++){
      bf8v af = *(const bf8v*)&AO[(mf*16+ln)*64 + kof];
      pr[mf] = __builtin_amdgcn_mfma_f32_16x16x32_bf16(af, bfo, pr[mf], 0,0,0);
    }
  }
  float v1[4][4]; float s1=0.f, s2=0.f;
  #pragma unroll
  for(int mf=0;mf<4;mf++){
    float4 ab = *(const float4*)&aob[l*64 + mf*16+quad*4];
    float av[4]={ab.x,ab.y,ab.z,ab.w};
    uint2 rx = *(const uint2*)&Xin[(size_t)(tok0+ln)*64 + mf*16+quad*4];
    float rr[4]; unpack4(rx, rr);
    #pragma unroll
    for(int r=0;r<4;r++){ float t=pr[mf][r]+av[r]+rr[r]; v1[mf][r]=t; s1+=t; s2+=t*t; }
  }
  s1 += __shfl_xor(s1,16,64); s1 += __shfl_xor(s1,32,64);
  s2 += __shfl_xor(s2,16,64); s2 += __shfl_xor(s2,32,64);
  float mean = s1*0.015625f, var = s2*0.015625f - mean*mean, rstd = rsqrtf(var+1e-5f);
  float x1[4][4];
  #pragma unroll
  for(int mf=0;mf<4;mf++){
    float4 lw = *(const float4*)&l1wg[l*64 + mf*16+quad*4];
    float4 lb = *(const float4*)&l1bg[l*64 + mf*16+quad*4];
    float wv[4]={lw.x,lw.y,lw.z,lw.w}, bv[4]={lb.x,lb.y,lb.z,lb.w};
    #pragma unroll
    for(int r=0;r<4;r++) x1[mf][r]=(v1[mf][r]-mean)*rstd*wv[r]+bv[r];
    *(uint2*)&sX[ln*72 + mf*16+quad*4] = pack4(x1[mf]);  // all waves write identical
  }
  // ---- FFN1: wave w -> hidden [64w, 64w+64) (same-wave sX RAW, no barrier) ----
  const ushort* W1 = wb + OFF_FW1 + l*16384;
  f4v f1[4];
  #pragma unroll
  for(int m=0;m<4;m++) f1[m]=(f4v){0,0,0,0};
  #pragma unroll
  for(int ks=0;ks<2;ks++){
    const int kof = ks*32+quad*8;
    bf8v bfx = *(const bf8v*)&sX[ln*72 + kof];
    #pragma unroll
    for(int mf=0;mf<4;mf++){
      bf8v af = *(const bf8v*)&W1[((w*4+mf)*16+ln)*64 + kof];
      f1[mf] = __builtin_amdgcn_mfma_f32_16x16x32_bf16(af, bfx, f1[mf], 0,0,0);
    }
  }
  #pragma unroll
  for(int mf=0;mf<4;mf++){
    const int f0 = (w*4+mf)*16+quad*4;
    float4 bb = *(const float4*)&fb1g[l*256 + f0];
    float h[4] = { fmaxf(f1[mf][0]+bb.x,0.f), fmaxf(f1[mf][1]+bb.y,0.f),
                   fmaxf(f1[mf][2]+bb.z,0.f), fmaxf(f1[mf][3]+bb.w,0.f) };
    *(uint2*)&sHH[ln*264 + f0] = pack4(h);
  }
  __syncthreads();
  // ---- FFN2: wave w -> features [16w,16w+16), K=256 ----
  const ushort* W2 = wb + OFF_FW2 + l*16384;
  f4v f2=(f4v){0,0,0,0};
  #pragma unroll
  for(int ks=0;ks<8;ks++){
    const int kof = ks*32+quad*8;
    bf8v bfh = *(const bf8v*)&sHH[ln*264 + kof];
    bf8v af = *(const bf8v*)&W2[(w*16+ln)*256 + kof];
    f2 = __builtin_amdgcn_mfma_f32_16x16x32_bf16(af, bfh, f2, 0,0,0);
  }
  float v2[4]; s1=0.f; s2=0.f;
  {
    float4 bb = *(const float4*)&fb2g[l*64 + w*16+quad*4];
    float bv[4]={bb.x,bb.y,bb.z,bb.w};
    #pragma unroll
    for(int r=0;r<4;r++){ float t=f2[r]+bv[r]+x1[w][r]; v2[r]=t; s1+=t; s2+=t*t; }
  }
  s1 += __shfl_xor(s1,16,64); s1 += __shfl_xor(s1,32,64);
  s2 += __shfl_xor(s2,16,64); s2 += __shfl_xor(s2,32,64);
  if(quad==0) sStat[w][ln] = make_float2(s1,s2);
  __syncthreads();
  {
    float t1=0.f,t2=0.f;
    #pragma unroll
    for(int ww=0;ww<4;ww++){ float2 st=sStat[ww][ln]; t1+=st.x; t2+=st.y; }
    mean = t1*0.015625f; var = t2*0.015625f - mean*mean; rstd = rsqrtf(var+1e-5f);
  }
  {
    float4 lw = *(const float4*)&l2wg[l*64 + w*16+quad*4];
    float4 lb = *(const float4*)&l2bg[l*64 + w*16+quad*4];
    float wv[4]={lw.x,lw.y,lw.z,lw.w}, bv[4]={lb.x,lb.y,lb.z,lb.w};
    float xo[4];
    #pragma unroll
    for(int r=0;r<4;r++) xo[r]=(v2[r]-mean)*rstd*wv[r]+bv[r];
    uint2 u = pack4(xo);
    *(uint2*)&Xout[(size_t)(tok0+ln)*64 + w*16+quad*4] = u;
    if(DOQ) *(uint2*)&sX[ln*72 + w*16+quad*4] = u;
  }
  // ---- QKV for next layer: 12 frags split 3/wave ----
  if(DOQ){
    __syncthreads();
    const ushort* Wq = wb + OFF_QKV_W + (l+1)*12288;
    const float* bq = bqn + (l+1)*192;
    f4v aq[3];
    #pragma unroll
    for(int m=0;m<3;m++) aq[m]=(f4v){0,0,0,0};
    #pragma unroll
    for(int ks=0;ks<2;ks++){
      const int kof = ks*32+quad*8;
      bf8v bfx = *(const bf8v*)&sX[ln*72 + kof];
      #pragma unroll
      for(int i=0;i<3;i++){
        bf8v af = *(const bf8v*)&Wq[((w*3+i)*16+ln)*64 + kof];
        aq[i] = __builtin_amdgcn_mfma_f32_16x16x32_bf16(af, bfx, aq[i], 0,0,0);
      }
    }
    #pragma unroll
    for(int i=0;i<3;i++){
      const int gm = w*3+i;
      if(gm < 4){
        float4 bb = *(const float4*)&bq[gm*16+quad*4];
        float o[4] = { aq[i][0]+bb.x*QS, aq[i][1]+bb.y*QS, aq[i][2]+bb.z*QS, aq[i][3]+bb.w*QS };
        *(uint2*)&QCn[((size_t)(b*4+gm)*1024 + tok0+ln)*16 + quad*4] = pack4(o);
      } else if(gm < 8){
        float4 bb = *(const float4*)&bq[gm*16+quad*4];
        float o[4] = { aq[i][0]+bb.x, aq[i][1]+bb.y, aq[i][2]+bb.z, aq[i][3]+bb.w };
        *(uint2*)&KCn[((size_t)(b*4+gm-4)*1024 + tok0+ln)*16 + quad*4] = pack4(o);
      } else {
        const int h2 = gm-8;
        float4 bb = *(const float4*)&bq[128 + h2*16 + quad*4];
        float bv[4]={bb.x,bb.y,bb.z,bb.w};
        #pragma unroll
        for(int r=0;r<4;r++)
          VTn[(size_t)((b*4+h2)*16 + quad*4+r)*1024 + tok0+ln] = bf16_rne(aq[i][r]+bv[r]);
      }
    }
  }
}

// ---------------- output head: 3840 blocks x 1 wave (token-group x chunk) ----------------
__global__ __launch_bounds__(64) void k_out(
    const ushort* __restrict__ X, const ushort* __restrict__ wb,
    const float* __restrict__ ob1g,
    const float* __restrict__ b20, const float* __restrict__ b21,
    const float* __restrict__ b22, const float* __restrict__ b23,
    float* __restrict__ out0, float* __restrict__ slots)
{
  __shared__ ushort sH[16*136];
  const int lane=threadIdx.x, ln=lane&15, quad=lane>>4;
  const int bid=blockIdx.x;
  const int b = bid/240;
  int r = bid - b*240;
  int seg, tg, ch;
  if(r<16){ seg=0; tg=r; ch=0; }
  else if(r<48){ seg=1; r-=16; tg=r>>1; ch=r&1; }
  else if(r<112){ seg=2; r-=48; tg=r>>2; ch=r&3; }
  else { seg=3; r-=112; tg=r>>3; ch=r&7; }
  const int tok0 = b*1024 + seg*256 + tg*16;
  const ushort* W1 = wb + OFF_OUT_W1 + seg*8192;
  const ushort* W2 = wb + OFF_OUT_W2 + seg_w1off(seg) + (size_t)(ch*64)*128;
  const float* b1 = ob1g + seg*128;
  const float* b2 = (seg==0?b20: seg==1?b21: seg==2?b22: b23) + ch*64;

  f4v a1[8];
  #pragma unroll
  for(int m=0;m<8;m++) a1[m]=(f4v){0,0,0,0};
  #pragma unroll
  for(int ks=0;ks<2;ks++){
    const int kof = ks*32+quad*8;
    bf8v bfx = *(const bf8v*)&X[(size_t)(tok0+ln)*64 + kof];
    #pragma unroll
    for(int mf=0;mf<8;mf++){
      bf8v af = *(const bf8v*)&W1[(mf*16+ln)*64 + kof];
      a1[mf] = __builtin_amdgcn_mfma_f32_16x16x32_bf16(af, bfx, a1[mf], 0,0,0);
    }
  }
  #pragma unroll
  for(int mf=0;mf<8;mf++){
    float4 bb = *(const float4*)&b1[mf*16+quad*4];
    float h[4] = { fast_tanh(a1[mf][0]+bb.x), fast_tanh(a1[mf][1]+bb.y),
                   fast_tanh(a1[mf][2]+bb.z), fast_tanh(a1[mf][3]+bb.w) };
    *(uint2*)&sH[ln*136 + mf*16+quad*4] = pack4(h);
  }
  f4v a2[4];
  #pragma unroll
  for(int m=0;m<4;m++) a2[m]=(f4v){0,0,0,0};
  #pragma unroll
  for(int ks=0;ks<4;ks++){
    const int kof = ks*32+quad*8;
    bf8v bfh = *(const bf8v*)&sH[ln*136 + kof];
    #pragma unroll
    for(int mf=0;mf<4;mf++){
      bf8v af = *(const bf8v*)&W2[(size_t)(mf*16+ln)*128 + kof];
      a2[mf] = __builtin_amdgcn_mfma_f32_16x16x32_bf16(af, bfh, a2[mf], 0,0,0);
    }
  }
  float keacc=0.f;
  #pragma unroll
  for(int mf=0;mf<4;mf++){
    float4 bb = *(const float4*)&b2[mf*16+quad*4];
    float d0=a2[mf][0]+bb.x, d1=a2[mf][1]+bb.y, d2=a2[mf][2]+bb.z, d3=a2[mf][3]+bb.w;
    keacc += (d0*d0+d1*d1)+(d2*d2+d3*d3);
    float4 o = {d0,d1,d2,d3};
    *(float4*)&out0[(size_t)(tok0+ln)*512 + ch*64 + mf*16+quad*4] = o;
  }
  float tot = wave_reduce_sum(keacc);
  if(lane==0) slots[bid] = 0.5f*tot;
}

// ---------------- ke reduction ----------------
__global__ __launch_bounds__(1024) void k_ke(const float* __restrict__ slots, float* __restrict__ keo){
  const int w = threadIdx.x>>6, lane = threadIdx.x&63;
  float s = 0.f;
  for(int i=lane;i<240;i+=64) s += slots[w*240 + i];
  s = wave_reduce_sum(s);
  if(lane==0) keo[w] = s;
}

// ---------------- launch ----------------
extern "C" void kernel_launch(void* const* d_in, const int* in_sizes, int n_in,
                              void* d_out, int out_size, void* d_ws, size_t ws_size,
                              hipStream_t stream)
{
  const float* y      = (const float*)d_in[1];
  const float* w1s[4] = {(const float*)d_in[3],(const float*)d_in[4],(const float*)d_in[5],(const float*)d_in[6]};
  const float* w2s[4] = {(const float*)d_in[7],(const float*)d_in[8],(const float*)d_in[9],(const float*)d_in[10]};
  const float* b2s[4] = {(const float*)d_in[11],(const float*)d_in[12],(const float*)d_in[13],(const float*)d_in[14]};
  const float* in_b1  = (const float*)d_in[15];
  const float* in_w2  = (const float*)d_in[16];
  const float* in_b2  = (const float*)d_in[17];
  const float* out_w1 = (const float*)d_in[18];
  const float* out_b1 = (const float*)d_in[19];
  const float* qkv_w  = (const float*)d_in[20];
  const float* qkv_b  = (const float*)d_in[21];
  const float* ao_w   = (const float*)d_in[22];
  const float* ao_b   = (const float*)d_in[23];
  const float* ln1w   = (const float*)d_in[24];
  const float* ln1b   = (const float*)d_in[25];
  const float* fw1    = (const float*)d_in[26];
  const float* fb1    = (const float*)d_in[27];
  const float* fw2    = (const float*)d_in[28];
  const float* fb2    = (const float*)d_in[29];
  const float* ln2w   = (const float*)d_in[30];
  const float* ln2b   = (const float*)d_in[31];

  float* out0 = (float*)d_out;
  float* keo  = out0 + (size_t)16*1024*512;

  ushort* wb  = (ushort*)d_ws;
  ushort* XA  = wb + OFF_XA;
  ushort* XB  = wb + OFF_XB;
  ushort* QC0 = wb + OFF_QC0;
  ushort* KC0 = wb + OFF_KC0;
  ushort* VT0 = wb + OFF_VT0;
  ushort* QC1 = wb + OFF_QC1;
  ushort* KC1 = wb + OFF_KC1;
  ushort* VT1 = wb + OFF_VT1;
  float* slots = (float*)(wb + OFF_KE);

  k_setup<<<1024,256,0,stream>>>(w1s[0],w1s[1],w1s[2],w1s[3], in_w2, out_w1,
      w2s[0],w2s[1],w2s[2],w2s[3], qkv_w, ao_w, fw1, fw2, wb, out0);

  k_in<<<1024,64,0,stream>>>(y, in_b1, in_b2, qkv_b, wb, XA, QC0, KC0, VT0);

  k_af<true><<<1024,256,0,stream>>>(XA, wb, 0, ao_b, ln1w, ln1b, fb1, fb2, ln2w, ln2b,
                                    XB, QC0, KC0, VT0, QC1, KC1, VT1, qkv_b);
  k_af<false><<<1024,256,0,stream>>>(XB, wb, 1, ao_b, ln1w, ln1b, fb1, fb2, ln2w, ln2b,
                                     XA, QC1, KC1, VT1, QC1, KC1, VT1, qkv_b);

  k_out<<<3840,64,0,stream>>>(XA, wb, out_b1, b2s[0],b2s[1],b2s[2],b2s[3], out0, slots);
  k_ke<<<1,1024,0,stream>>>(slots, keo);
}

// Round 7
// 260.853 us; speedup vs baseline: 2.4800x; 1.1045x over previous
//
#include <hip/hip_runtime.h>
#include <math.h>

typedef short bf8v __attribute__((ext_vector_type(8)));
typedef short bf4v __attribute__((ext_vector_type(4)));
typedef float f4v  __attribute__((ext_vector_type(4)));

#define QS 0.36067376022224085f  // log2(e)/4

// ---- ws layout (ushort units) ----
#define OFF_IN_W1  0        // per-seg {0,8192,24576,57344}, [128][F]
#define OFF_IN_W2  122880   // + seg*8192, [64][128]
#define OFF_OUT_W1 155648   // + seg*8192, [128][64]
#define OFF_OUT_W2 188416   // per-seg {0,8192,24576,57344}, [F][128]
#define OFF_QKV_W  311296   // + l*12288, [192][64] (Q rows pre-scaled by QS)
#define OFF_AO_W   335872   // + l*4096,  [64][64]
#define OFF_FW1    344064   // + l*16384, [256][64]
#define OFF_FW2    376832   // + l*16384, [64][256]
#define WTOT       409600
#define OFF_XA     409600
#define OFF_XB     1458176
#define OFF_QC0    2506752  // [b][h][1024][16] bf16 (Q prescaled)
#define OFF_KC0    3555328  // [b][h][1024][16]
#define OFF_VB0    4603904  // [b][h][chunk64][d16][k16]
#define OFF_QC1    5652480
#define OFF_KC1    6701056
#define OFF_VB1    7749632
#define OFF_KE     8798208  // 3840 floats

__device__ __forceinline__ ushort bf16_rne(float f){
  uint u = __float_as_uint(f);
  u += 0x7fffu + ((u>>16)&1u);
  return (ushort)(u>>16);
}
__device__ __forceinline__ uint pack2(float a, float b){
  uint ua = __float_as_uint(a); ua += 0x7fffu + ((ua>>16)&1u);
  uint ub = __float_as_uint(b); ub += 0x7fffu + ((ub>>16)&1u);
  return __builtin_amdgcn_perm(ub, ua, 0x07060302u);
}
__device__ __forceinline__ uint pack2t(float a, float b){   // truncation pack (P only)
  return __builtin_amdgcn_perm(__float_as_uint(b), __float_as_uint(a), 0x07060302u);
}
__device__ __forceinline__ float bf2f(uint u){ return __uint_as_float(u<<16); }
__device__ __forceinline__ uint2 pack4(const float v[4]){
  uint2 r; r.x = pack2(v[0],v[1]); r.y = pack2(v[2],v[3]); return r;
}
__device__ __forceinline__ void unpack4(uint2 p, float v[4]){
  v[0]=bf2f(p.x&0xffffu); v[1]=bf2f(p.x>>16); v[2]=bf2f(p.y&0xffffu); v[3]=bf2f(p.y>>16);
}
__device__ __forceinline__ float wave_reduce_sum(float v){
  #pragma unroll
  for(int o=32;o>0;o>>=1) v += __shfl_xor(v, o, 64);
  return v;
}
__device__ __forceinline__ float fast_tanh(float x){
  float t = __builtin_amdgcn_exp2f(2.8853900817779268f*x);
  return (t-1.f)*__builtin_amdgcn_rcpf(t+1.f);
}
__device__ __forceinline__ int seg_w1off(int seg){
  return (seg==0)?0:(seg==1)?8192:(seg==2)?24576:57344;
}
__device__ __forceinline__ f4v mfma16(bf4v a, bf4v b, f4v c){
#if __has_builtin(__builtin_amdgcn_mfma_f32_16x16x16bf16_1k)
  return __builtin_amdgcn_mfma_f32_16x16x16bf16_1k(a, b, c, 0, 0, 0);
#else
  f4v d;
  asm("v_mfma_f32_16x16x16_bf16 %0, %1, %2, %3" : "=v"(d) : "v"(a), "v"(b), "v"(c));
  return d;
#endif
}

// ---------------- setup: weights->bf16 + out0 pad zero ----------------
__global__ __launch_bounds__(256) void k_setup(
    const float* __restrict__ iw10, const float* __restrict__ iw11,
    const float* __restrict__ iw12, const float* __restrict__ iw13,
    const float* __restrict__ iw2,  const float* __restrict__ ow1,
    const float* __restrict__ ow20, const float* __restrict__ ow21,
    const float* __restrict__ ow22, const float* __restrict__ ow23,
    const float* __restrict__ qkvw, const float* __restrict__ aow,
    const float* __restrict__ f1,   const float* __restrict__ f2,
    ushort* __restrict__ wb, float* __restrict__ out0)
{
  const int tid = threadIdx.x;
  if(blockIdx.x < 512){
    for(int i = blockIdx.x*256 + tid; i < WTOT; i += 512*256){
      float v; int j = i;
      if(j < 122880){
        if(j<8192) v=iw10[j];
        else if(j<24576) v=iw11[j-8192];
        else if(j<57344) v=iw12[j-24576];
        else v=iw13[j-57344];
      } else if(j < 155648) v = iw2[j-122880];
      else if(j < 188416) v = ow1[j-155648];
      else if(j < 311296){
        j -= 188416;
        if(j<8192) v=ow20[j];
        else if(j<24576) v=ow21[j-8192];
        else if(j<57344) v=ow22[j-24576];
        else v=ow23[j-57344];
      } else if(j < 335872){
        j -= 311296; v = qkvw[j];
        if(((j>>6)%192) < 64) v *= QS;
      } else if(j < 344064) v = aow[j-335872];
      else if(j < 376832) v = f1[j-344064];
      else v = f2[j-376832];
      wb[i] = bf16_rne(v);
    }
  } else {
    for(int i = (blockIdx.x-512)*256 + tid; i < 16384*112; i += 512*256){
      int t = i/112, c = 64 + (i%112)*4;
      int F = 64 << ((t>>8)&3);
      if(c >= F){ float4 z={0,0,0,0}; *(float4*)&out0[(size_t)t*512 + c] = z; }
    }
  }
}

// ---------------- input MLP + QKV(l=0): 1024 blocks x 1 wave x 16 tokens ----------------
__global__ __launch_bounds__(64) void k_in(
    const float* __restrict__ y, const float* __restrict__ b1g, const float* __restrict__ b2g,
    const float* __restrict__ bqg, const ushort* __restrict__ wb,
    ushort* __restrict__ X, ushort* __restrict__ QC, ushort* __restrict__ KC,
    ushort* __restrict__ VB)
{
  __shared__ ushort sH[16*136];
  __shared__ ushort sX[16*72];
  const int lane=threadIdx.x, ln=lane&15, quad=lane>>4;
  const int tok0=blockIdx.x*16;
  const int seg=(tok0>>8)&3, F=64<<seg, b=tok0>>10;
  const int tg = blockIdx.x & 63;
  const ushort* W1 = wb + OFF_IN_W1 + seg_w1off(seg);
  const ushort* W2 = wb + OFF_IN_W2 + seg*8192;
  const ushort* Wq = wb + OFF_QKV_W;
  const float* b1 = b1g + seg*128;
  const float* b2 = b2g + seg*64;

  f4v a1[8];
  #pragma unroll
  for(int m=0;m<8;m++) a1[m]=(f4v){0,0,0,0};
  const int nk = F>>5;
  for(int ks=0; ks<nk; ks++){
    const int kof = ks*32 + quad*8;
    const float* yp = &y[(size_t)(tok0+ln)*512 + kof];
    float4 a = *(const float4*)yp;
    float4 c = *(const float4*)(yp+4);
    union{bf8v v; uint us[4];} u;
    u.us[0]=pack2(a.x,a.y); u.us[1]=pack2(a.z,a.w);
    u.us[2]=pack2(c.x,c.y); u.us[3]=pack2(c.z,c.w);
    #pragma unroll
    for(int mf=0;mf<8;mf++){
      bf8v af = *(const bf8v*)&W1[(size_t)(mf*16+ln)*F + kof];
      a1[mf] = __builtin_amdgcn_mfma_f32_16x16x32_bf16(af, u.v, a1[mf], 0,0,0);
    }
  }
  #pragma unroll
  for(int mf=0;mf<8;mf++){
    float4 bb = *(const float4*)&b1[mf*16+quad*4];
    float h[4] = { fast_tanh(a1[mf][0]+bb.x), fast_tanh(a1[mf][1]+bb.y),
                   fast_tanh(a1[mf][2]+bb.z), fast_tanh(a1[mf][3]+bb.w) };
    *(uint2*)&sH[ln*136 + mf*16+quad*4] = pack4(h);
  }
  f4v a2[4];
  #pragma unroll
  for(int m=0;m<4;m++) a2[m]=(f4v){0,0,0,0};
  #pragma unroll
  for(int ks=0;ks<4;ks++){
    const int kof = ks*32+quad*8;
    bf8v bfh = *(const bf8v*)&sH[ln*136 + kof];
    #pragma unroll
    for(int mf=0;mf<4;mf++){
      bf8v af = *(const bf8v*)&W2[(mf*16+ln)*128 + kof];
      a2[mf] = __builtin_amdgcn_mfma_f32_16x16x32_bf16(af, bfh, a2[mf], 0,0,0);
    }
  }
  #pragma unroll
  for(int mf=0;mf<4;mf++){
    float4 bb = *(const float4*)&b2[mf*16+quad*4];
    float o[4] = { a2[mf][0]+bb.x, a2[mf][1]+bb.y, a2[mf][2]+bb.z, a2[mf][3]+bb.w };
    uint2 u = pack4(o);
    *(uint2*)&X[(size_t)(tok0+ln)*64 + mf*16+quad*4] = u;
    *(uint2*)&sX[ln*72 + mf*16+quad*4] = u;
  }
  // QKV tail (layer 0)
  f4v aq[12];
  #pragma unroll
  for(int m=0;m<12;m++) aq[m]=(f4v){0,0,0,0};
  #pragma unroll
  for(int ks=0;ks<2;ks++){
    const int kof = ks*32+quad*8;
    bf8v bfx = *(const bf8v*)&sX[ln*72 + kof];
    #pragma unroll
    for(int mf=0;mf<12;mf++){
      bf8v af = *(const bf8v*)&Wq[(mf*16+ln)*64 + kof];
      aq[mf] = __builtin_amdgcn_mfma_f32_16x16x32_bf16(af, bfx, aq[mf], 0,0,0);
    }
  }
  #pragma unroll
  for(int mf=0;mf<4;mf++){   // Q (prescaled weights; scale bias too)
    float4 bb = *(const float4*)&bqg[mf*16+quad*4];
    float o[4] = { aq[mf][0]+bb.x*QS, aq[mf][1]+bb.y*QS, aq[mf][2]+bb.z*QS, aq[mf][3]+bb.w*QS };
    *(uint2*)&QC[((size_t)(b*4+mf)*1024 + tok0+ln)*16 + quad*4] = pack4(o);
  }
  #pragma unroll
  for(int mf=4;mf<8;mf++){   // K
    float4 bb = *(const float4*)&bqg[mf*16+quad*4];
    float o[4] = { aq[mf][0]+bb.x, aq[mf][1]+bb.y, aq[mf][2]+bb.z, aq[mf][3]+bb.w };
    *(uint2*)&KC[((size_t)(b*4+mf-4)*1024 + tok0+ln)*16 + quad*4] = pack4(o);
  }
  #pragma unroll
  for(int mf=8;mf<12;mf++){  // V blocked [bh][chunk][d16][k16]
    const int h = mf-8;
    float4 bb = *(const float4*)&bqg[128 + h*16 + quad*4];
    float bv[4]={bb.x,bb.y,bb.z,bb.w};
    #pragma unroll
    for(int r=0;r<4;r++)
      VB[(size_t)(b*4+h)*16384 + tg*256 + (quad*4+r)*16 + ln] = bf16_rne(aq[mf][r]+bv[r]);
  }
}

// ---------------- fused attn+proj+LN1+FFN1+FFN2+LN2(+QKV next) ----------------
// 1024 blocks x 4 waves x 16 tokens; wave = head during attention. Attention is LDS-free.
template<bool DOQ>
__global__ __launch_bounds__(256) void k_af(
    const ushort* __restrict__ Xin, const ushort* __restrict__ wb, int l,
    const float* __restrict__ aob, const float* __restrict__ l1wg, const float* __restrict__ l1bg,
    const float* __restrict__ fb1g, const float* __restrict__ fb2g,
    const float* __restrict__ l2wg, const float* __restrict__ l2bg,
    ushort* __restrict__ Xout,
    const ushort* __restrict__ QC, const ushort* __restrict__ KC, const ushort* __restrict__ VB,
    ushort* __restrict__ QCn, ushort* __restrict__ KCn, ushort* __restrict__ VBn,
    const float* __restrict__ bqn)
{
  __shared__ ushort sO[16*72];
  __shared__ ushort sX[16*72];
  __shared__ ushort sHH[16*264];
  __shared__ float2 sStat[4][16];
  const int tid=threadIdx.x, lane=tid&63, w=tid>>6, ln=lane&15, quad=lane>>4;
  const int tok0=blockIdx.x*16, b=tok0>>10;
  const int tg = blockIdx.x & 63;
  const ushort* QCh = QC + (size_t)(b*4+w)*16384;
  const ushort* KCh = KC + (size_t)(b*4+w)*16384;
  const ushort* VBh = VB + (size_t)(b*4+w)*16384;

  // ---- attention (wave w = head w, 16 q rows), K=16 MFMA chunks, no LDS ----
  bf4v qf = *(const bf4v*)&QCh[(size_t)(tok0+ln)*16 + quad*4];
  f4v oa0=(f4v){0,0,0,0}, oa1=(f4v){0,0,0,0};
  float l0=0.f, l1=0.f;
  #pragma unroll 8
  for(int kc=0;kc<64;kc++){
    bf4v kf = *(const bf4v*)&KCh[(kc*16+ln)*16 + quad*4];
    bf4v vf = *(const bf4v*)&VBh[kc*256 + ln*16 + quad*4];
    f4v st = mfma16(kf, qf, (f4v){0,0,0,0});     // S^T chunk: lane = (q=ln, keys quad*4+r)
    float p0=__builtin_amdgcn_exp2f(st[0]);
    float p1=__builtin_amdgcn_exp2f(st[1]);
    float p2=__builtin_amdgcn_exp2f(st[2]);
    float p3=__builtin_amdgcn_exp2f(st[3]);
    union{bf4v v; uint2 u;} pa;
    pa.u.x = pack2t(p0,p1); pa.u.y = pack2t(p2,p3);  // C-layout == PV A-frag layout
    if(kc&1){ l1 += (p0+p1)+(p2+p3); oa1 = mfma16(pa.v, vf, oa1); }
    else    { l0 += (p0+p1)+(p2+p3); oa0 = mfma16(pa.v, vf, oa0); }
  }
  f4v oacc = oa0 + oa1;
  {
    float lq = l0 + l1;
    lq += __shfl_xor(lq, 16, 64);
    lq += __shfl_xor(lq, 32, 64);
    #pragma unroll
    for(int r=0;r<4;r++){
      float lr = __shfl(lq, quad*4+r, 64);
      float ov = oacc[r]*__builtin_amdgcn_rcpf(lr);
      sO[(quad*4+r)*72 + w*16 + ln] = bf16_rne(ov);   // O[q][h*16+d]
    }
  }
  __syncthreads();

  // ---- proj + residual + LN1 (full 64 features per wave, duplicated) ----
  const ushort* AO = wb + OFF_AO_W + l*4096;
  f4v pr[4];
  #pragma unroll
  for(int m=0;m<4;m++) pr[m]=(f4v){0,0,0,0};
  #pragma unroll
  for(int ks=0;ks<2;ks++){
    const int kof = ks*32+quad*8;
    bf8v bfo = *(const bf8v*)&sO[ln*72 + kof];
    #pragma unroll
    for(int mf=0;mf<4;mf++){
      bf8v af = *(const bf8v*)&AO[(mf*16+ln)*64 + kof];
      pr[mf] = __builtin_amdgcn_mfma_f32_16x16x32_bf16(af, bfo, pr[mf], 0,0,0);
    }
  }
  float v1[4][4]; float s1=0.f, s2=0.f;
  #pragma unroll
  for(int mf=0;mf<4;mf++){
    float4 ab = *(const float4*)&aob[l*64 + mf*16+quad*4];
    float av[4]={ab.x,ab.y,ab.z,ab.w};
    uint2 rx = *(const uint2*)&Xin[(size_t)(tok0+ln)*64 + mf*16+quad*4];
    float rr[4]; unpack4(rx, rr);
    #pragma unroll
    for(int r=0;r<4;r++){ float t=pr[mf][r]+av[r]+rr[r]; v1[mf][r]=t; s1+=t; s2+=t*t; }
  }
  s1 += __shfl_xor(s1,16,64); s1 += __shfl_xor(s1,32,64);
  s2 += __shfl_xor(s2,16,64); s2 += __shfl_xor(s2,32,64);
  float mean = s1*0.015625f, var = s2*0.015625f - mean*mean, rstd = rsqrtf(var+1e-5f);
  float x1[4][4];
  #pragma unroll
  for(int mf=0;mf<4;mf++){
    float4 lw = *(const float4*)&l1wg[l*64 + mf*16+quad*4];
    float4 lb = *(const float4*)&l1bg[l*64 + mf*16+quad*4];
    float wv[4]={lw.x,lw.y,lw.z,lw.w}, bv[4]={lb.x,lb.y,lb.z,lb.w};
    #pragma unroll
    for(int r=0;r<4;r++) x1[mf][r]=(v1[mf][r]-mean)*rstd*wv[r]+bv[r];
    *(uint2*)&sX[ln*72 + mf*16+quad*4] = pack4(x1[mf]);  // all waves write identical
  }
  // ---- FFN1: wave w -> hidden [64w, 64w+64) (same-wave sX RAW, no barrier) ----
  const ushort* W1 = wb + OFF_FW1 + l*16384;
  f4v f1[4];
  #pragma unroll
  for(int m=0;m<4;m++) f1[m]=(f4v){0,0,0,0};
  #pragma unroll
  for(int ks=0;ks<2;ks++){
    const int kof = ks*32+quad*8;
    bf8v bfx = *(const bf8v*)&sX[ln*72 + kof];
    #pragma unroll
    for(int mf=0;mf<4;mf++){
      bf8v af = *(const bf8v*)&W1[((w*4+mf)*16+ln)*64 + kof];
      f1[mf] = __builtin_amdgcn_mfma_f32_16x16x32_bf16(af, bfx, f1[mf], 0,0,0);
    }
  }
  #pragma unroll
  for(int mf=0;mf<4;mf++){
    const int f0 = (w*4+mf)*16+quad*4;
    float4 bb = *(const float4*)&fb1g[l*256 + f0];
    float h[4] = { fmaxf(f1[mf][0]+bb.x,0.f), fmaxf(f1[mf][1]+bb.y,0.f),
                   fmaxf(f1[mf][2]+bb.z,0.f), fmaxf(f1[mf][3]+bb.w,0.f) };
    *(uint2*)&sHH[ln*264 + f0] = pack4(h);
  }
  __syncthreads();
  // ---- FFN2: wave w -> features [16w,16w+16), K=256 ----
  const ushort* W2 = wb + OFF_FW2 + l*16384;
  f4v f2=(f4v){0,0,0,0};
  #pragma unroll
  for(int ks=0;ks<8;ks++){
    const int kof = ks*32+quad*8;
    bf8v bfh = *(const bf8v*)&sHH[ln*264 + kof];
    bf8v af = *(const bf8v*)&W2[(w*16+ln)*256 + kof];
    f2 = __builtin_amdgcn_mfma_f32_16x16x32_bf16(af, bfh, f2, 0,0,0);
  }
  float v2[4]; s1=0.f; s2=0.f;
  {
    float4 bb = *(const float4*)&fb2g[l*64 + w*16+quad*4];
    float bv[4]={bb.x,bb.y,bb.z,bb.w};
    #pragma unroll
    for(int r=0;r<4;r++){ float t=f2[r]+bv[r]+x1[w][r]; v2[r]=t; s1+=t; s2+=t*t; }
  }
  s1 += __shfl_xor(s1,16,64); s1 += __shfl_xor(s1,32,64);
  s2 += __shfl_xor(s2,16,64); s2 += __shfl_xor(s2,32,64);
  if(quad==0) sStat[w][ln] = make_float2(s1,s2);
  __syncthreads();
  {
    float t1=0.f,t2=0.f;
    #pragma unroll
    for(int ww=0;ww<4;ww++){ float2 st=sStat[ww][ln]; t1+=st.x; t2+=st.y; }
    mean = t1*0.015625f; var = t2*0.015625f - mean*mean; rstd = rsqrtf(var+1e-5f);
  }
  {
    float4 lw = *(const float4*)&l2wg[l*64 + w*16+quad*4];
    float4 lb = *(const float4*)&l2bg[l*64 + w*16+quad*4];
    float wv[4]={lw.x,lw.y,lw.z,lw.w}, bv[4]={lb.x,lb.y,lb.z,lb.w};
    float xo[4];
    #pragma unroll
    for(int r=0;r<4;r++) xo[r]=(v2[r]-mean)*rstd*wv[r]+bv[r];
    uint2 u = pack4(xo);
    *(uint2*)&Xout[(size_t)(tok0+ln)*64 + w*16+quad*4] = u;
    if(DOQ) *(uint2*)&sX[ln*72 + w*16+quad*4] = u;
  }
  // ---- QKV for next layer: 12 frags split 3/wave ----
  if(DOQ){
    __syncthreads();
    const ushort* Wq = wb + OFF_QKV_W + (l+1)*12288;
    const float* bq = bqn + (l+1)*192;
    f4v aq[3];
    #pragma unroll
    for(int m=0;m<3;m++) aq[m]=(f4v){0,0,0,0};
    #pragma unroll
    for(int ks=0;ks<2;ks++){
      const int kof = ks*32+quad*8;
      bf8v bfx = *(const bf8v*)&sX[ln*72 + kof];
      #pragma unroll
      for(int i=0;i<3;i++){
        bf8v af = *(const bf8v*)&Wq[((w*3+i)*16+ln)*64 + kof];
        aq[i] = __builtin_amdgcn_mfma_f32_16x16x32_bf16(af, bfx, aq[i], 0,0,0);
      }
    }
    #pragma unroll
    for(int i=0;i<3;i++){
      const int gm = w*3+i;
      if(gm < 4){
        float4 bb = *(const float4*)&bq[gm*16+quad*4];
        float o[4] = { aq[i][0]+bb.x*QS, aq[i][1]+bb.y*QS, aq[i][2]+bb.z*QS, aq[i][3]+bb.w*QS };
        *(uint2*)&QCn[((size_t)(b*4+gm)*1024 + tok0+ln)*16 + quad*4] = pack4(o);
      } else if(gm < 8){
        float4 bb = *(const float4*)&bq[gm*16+quad*4];
        float o[4] = { aq[i][0]+bb.x, aq[i][1]+bb.y, aq[i][2]+bb.z, aq[i][3]+bb.w };
        *(uint2*)&KCn[((size_t)(b*4+gm-4)*1024 + tok0+ln)*16 + quad*4] = pack4(o);
      } else {
        const int h2 = gm-8;
        float4 bb = *(const float4*)&bq[128 + h2*16 + quad*4];
        float bv[4]={bb.x,bb.y,bb.z,bb.w};
        #pragma unroll
        for(int r=0;r<4;r++)
          VBn[(size_t)(b*4+h2)*16384 + tg*256 + (quad*4+r)*16 + ln] = bf16_rne(aq[i][r]+bv[r]);
      }
    }
  }
}

// ---------------- output head: 3840 blocks x 1 wave (token-group x chunk) ----------------
__global__ __launch_bounds__(64) void k_out(
    const ushort* __restrict__ X, const ushort* __restrict__ wb,
    const float* __restrict__ ob1g,
    const float* __restrict__ b20, const float* __restrict__ b21,
    const float* __restrict__ b22, const float* __restrict__ b23,
    float* __restrict__ out0, float* __restrict__ slots)
{
  __shared__ ushort sH[16*136];
  const int lane=threadIdx.x, ln=lane&15, quad=lane>>4;
  const int bid=blockIdx.x;
  const int b = bid/240;
  int r = bid - b*240;
  int seg, tg, ch;
  if(r<16){ seg=0; tg=r; ch=0; }
  else if(r<48){ seg=1; r-=16; tg=r>>1; ch=r&1; }
  else if(r<112){ seg=2; r-=48; tg=r>>2; ch=r&3; }
  else { seg=3; r-=112; tg=r>>3; ch=r&7; }
  const int tok0 = b*1024 + seg*256 + tg*16;
  const ushort* W1 = wb + OFF_OUT_W1 + seg*8192;
  const ushort* W2 = wb + OFF_OUT_W2 + seg_w1off(seg) + (size_t)(ch*64)*128;
  const float* b1 = ob1g + seg*128;
  const float* b2 = (seg==0?b20: seg==1?b21: seg==2?b22: b23) + ch*64;

  f4v a1[8];
  #pragma unroll
  for(int m=0;m<8;m++) a1[m]=(f4v){0,0,0,0};
  #pragma unroll
  for(int ks=0;ks<2;ks++){
    const int kof = ks*32+quad*8;
    bf8v bfx = *(const bf8v*)&X[(size_t)(tok0+ln)*64 + kof];
    #pragma unroll
    for(int mf=0;mf<8;mf++){
      bf8v af = *(const bf8v*)&W1[(mf*16+ln)*64 + kof];
      a1[mf] = __builtin_amdgcn_mfma_f32_16x16x32_bf16(af, bfx, a1[mf], 0,0,0);
    }
  }
  #pragma unroll
  for(int mf=0;mf<8;mf++){
    float4 bb = *(const float4*)&b1[mf*16+quad*4];
    float h[4] = { fast_tanh(a1[mf][0]+bb.x), fast_tanh(a1[mf][1]+bb.y),
                   fast_tanh(a1[mf][2]+bb.z), fast_tanh(a1[mf][3]+bb.w) };
    *(uint2*)&sH[ln*136 + mf*16+quad*4] = pack4(h);
  }
  f4v a2[4];
  #pragma unroll
  for(int m=0;m<4;m++) a2[m]=(f4v){0,0,0,0};
  #pragma unroll
  for(int ks=0;ks<4;ks++){
    const int kof = ks*32+quad*8;
    bf8v bfh = *(const bf8v*)&sH[ln*136 + kof];
    #pragma unroll
    for(int mf=0;mf<4;mf++){
      bf8v af = *(const bf8v*)&W2[(size_t)(mf*16+ln)*128 + kof];
      a2[mf] = __builtin_amdgcn_mfma_f32_16x16x32_bf16(af, bfh, a2[mf], 0,0,0);
    }
  }
  float keacc=0.f;
  #pragma unroll
  for(int mf=0;mf<4;mf++){
    float4 bb = *(const float4*)&b2[mf*16+quad*4];
    float d0=a2[mf][0]+bb.x, d1=a2[mf][1]+bb.y, d2=a2[mf][2]+bb.z, d3=a2[mf][3]+bb.w;
    keacc += (d0*d0+d1*d1)+(d2*d2+d3*d3);
    float4 o = {d0,d1,d2,d3};
    *(float4*)&out0[(size_t)(tok0+ln)*512 + ch*64 + mf*16+quad*4] = o;
  }
  float tot = wave_reduce_sum(keacc);
  if(lane==0) slots[bid] = 0.5f*tot;
}

// ---------------- ke reduction ----------------
__global__ __launch_bounds__(1024) void k_ke(const float* __restrict__ slots, float* __restrict__ keo){
  const int w = threadIdx.x>>6, lane = threadIdx.x&63;
  float s = 0.f;
  for(int i=lane;i<240;i+=64) s += slots[w*240 + i];
  s = wave_reduce_sum(s);
  if(lane==0) keo[w] = s;
}

// ---------------- launch ----------------
extern "C" void kernel_launch(void* const* d_in, const int* in_sizes, int n_in,
                              void* d_out, int out_size, void* d_ws, size_t ws_size,
                              hipStream_t stream)
{
  const float* y      = (const float*)d_in[1];
  const float* w1s[4] = {(const float*)d_in[3],(const float*)d_in[4],(const float*)d_in[5],(const float*)d_in[6]};
  const float* w2s[4] = {(const float*)d_in[7],(const float*)d_in[8],(const float*)d_in[9],(const float*)d_in[10]};
  const float* b2s[4] = {(const float*)d_in[11],(const float*)d_in[12],(const float*)d_in[13],(const float*)d_in[14]};
  const float* in_b1  = (const float*)d_in[15];
  const float* in_w2  = (const float*)d_in[16];
  const float* in_b2  = (const float*)d_in[17];
  const float* out_w1 = (const float*)d_in[18];
  const float* out_b1 = (const float*)d_in[19];
  const float* qkv_w  = (const float*)d_in[20];
  const float* qkv_b  = (const float*)d_in[21];
  const float* ao_w   = (const float*)d_in[22];
  const float* ao_b   = (const float*)d_in[23];
  const float* ln1w   = (const float*)d_in[24];
  const float* ln1b   = (const float*)d_in[25];
  const float* fw1    = (const float*)d_in[26];
  const float* fb1    = (const float*)d_in[27];
  const float* fw2    = (const float*)d_in[28];
  const float* fb2    = (const float*)d_in[29];
  const float* ln2w   = (const float*)d_in[30];
  const float* ln2b   = (const float*)d_in[31];

  float* out0 = (float*)d_out;
  float* keo  = out0 + (size_t)16*1024*512;

  ushort* wb  = (ushort*)d_ws;
  ushort* XA  = wb + OFF_XA;
  ushort* XB  = wb + OFF_XB;
  ushort* QC0 = wb + OFF_QC0;
  ushort* KC0 = wb + OFF_KC0;
  ushort* VB0 = wb + OFF_VB0;
  ushort* QC1 = wb + OFF_QC1;
  ushort* KC1 = wb + OFF_KC1;
  ushort* VB1 = wb + OFF_VB1;
  float* slots = (float*)(wb + OFF_KE);

  k_setup<<<1024,256,0,stream>>>(w1s[0],w1s[1],w1s[2],w1s[3], in_w2, out_w1,
      w2s[0],w2s[1],w2s[2],w2s[3], qkv_w, ao_w, fw1, fw2, wb, out0);

  k_in<<<1024,64,0,stream>>>(y, in_b1, in_b2, qkv_b, wb, XA, QC0, KC0, VB0);

  k_af<true><<<1024,256,0,stream>>>(XA, wb, 0, ao_b, ln1w, ln1b, fb1, fb2, ln2w, ln2b,
                                    XB, QC0, KC0, VB0, QC1, KC1, VB1, qkv_b);
  k_af<false><<<1024,256,0,stream>>>(XB, wb, 1, ao_b, ln1w, ln1b, fb1, fb2, ln2w, ln2b,
                                     XA, QC1, KC1, VB1, QC1, KC1, VB1, qkv_b);

  k_out<<<3840,64,0,stream>>>(XA, wb, out_b1, b2s[0],b2s[1],b2s[2],b2s[3], out0, slots);
  k_ke<<<1,1024,0,stream>>>(slots, keo);
}